// Round 8
// baseline (1175.823 us; speedup 1.0000x reference)
//
#include <hip/hip_runtime.h>
#include <math.h>

#define OBSD   256
#define TSEQ   4096
#define NBATCH 32
#define DMODEL 128
#define DSTATE 64
#define DINNER 256
#define NHEADS 4
#define HEADDIM 64
#define NPROJ  644
#define NTOK   (NBATCH*TSEQ)
#define CHUNK  128
#define NCHUNK (TSEQ/CHUNK)
#define NACT   64
#define BCW2   128   // bcbuf row width (B 64 | C 64)

__device__ __forceinline__ float siluf(float x) { return x / (1.f + __expf(-x)); }

// broadcast lane `lane`'s value to all lanes via v_readlane (VALU, no LDS unit)
__device__ __forceinline__ float rdlane(float v, int lane) {
    return __int_as_float(__builtin_amdgcn_readlane(__float_as_int(v), lane));
}

// ---------------------------------------------------------------------------
// fp32 tiled GEMM, A(MxK) row-major with row stride lda, B(KxN) row-major,
// C(MxN) row-major.  C = (A@B) * rowscale[r] + bias[c]  (either may be null)
// ---------------------------------------------------------------------------
template<int BM, int BN, int BK>
__launch_bounds__(256)
__global__ void gemm_rrr(const float* __restrict__ A, const float* __restrict__ B,
                         float* __restrict__ C, int M, int N, int K, int lda,
                         const float* __restrict__ bias, const float* __restrict__ rowscale)
{
    static_assert(BM == 128 && BN == 64 && BK == 16, "tile fixed");
    __shared__ float As[BK][BM + 4];
    __shared__ float Bs[BK][BN];
    const int tid = threadIdx.x;
    const int m0 = blockIdx.y * BM;
    const int n0 = blockIdx.x * BN;
    const int ty = tid >> 4;
    const int tx = tid & 15;

    float acc[8][4];
#pragma unroll
    for (int i = 0; i < 8; ++i)
#pragma unroll
        for (int j = 0; j < 4; ++j) acc[i][j] = 0.f;

    for (int k0 = 0; k0 < K; k0 += BK) {
#pragma unroll
        for (int l = 0; l < 2; ++l) {
            const int idx = tid + l * 256;
            const int r  = idx >> 2;
            const int c4 = (idx & 3) << 2;
            const float4 v = *(const float4*)(A + (size_t)(m0 + r) * lda + k0 + c4);
            As[c4 + 0][r] = v.x; As[c4 + 1][r] = v.y;
            As[c4 + 2][r] = v.z; As[c4 + 3][r] = v.w;
        }
        {
            const int r  = tid >> 4;
            const int c4 = (tid & 15) << 2;
            const int n  = n0 + c4;
            float4 v;
            if (n + 3 < N) {
                v = *(const float4*)(B + (size_t)(k0 + r) * N + n);
            } else {
                v.x = (n + 0) < N ? B[(size_t)(k0 + r) * N + n + 0] : 0.f;
                v.y = (n + 1) < N ? B[(size_t)(k0 + r) * N + n + 1] : 0.f;
                v.z = (n + 2) < N ? B[(size_t)(k0 + r) * N + n + 2] : 0.f;
                v.w = (n + 3) < N ? B[(size_t)(k0 + r) * N + n + 3] : 0.f;
            }
            *(float4*)&Bs[r][c4] = v;
        }
        __syncthreads();
#pragma unroll
        for (int kk = 0; kk < BK; ++kk) {
            const float4 a0 = *(const float4*)&As[kk][ty * 8];
            const float4 a1 = *(const float4*)&As[kk][ty * 8 + 4];
            const float4 b0 = *(const float4*)&Bs[kk][tx * 4];
            const float a[8] = {a0.x, a0.y, a0.z, a0.w, a1.x, a1.y, a1.z, a1.w};
            const float bb[4] = {b0.x, b0.y, b0.z, b0.w};
#pragma unroll
            for (int i = 0; i < 8; ++i)
#pragma unroll
                for (int j = 0; j < 4; ++j)
                    acc[i][j] = fmaf(a[i], bb[j], acc[i][j]);
        }
        __syncthreads();
    }

#pragma unroll
    for (int i = 0; i < 8; ++i) {
        const int r = m0 + ty * 8 + i;
        const float rs = rowscale ? rowscale[r] : 1.f;
        const int c = n0 + tx * 4;
        if (c + 3 < N) {
            float4 v;
            v.x = acc[i][0] * rs + (bias ? bias[c + 0] : 0.f);
            v.y = acc[i][1] * rs + (bias ? bias[c + 1] : 0.f);
            v.z = acc[i][2] * rs + (bias ? bias[c + 2] : 0.f);
            v.w = acc[i][3] * rs + (bias ? bias[c + 3] : 0.f);
            *(float4*)(C + (size_t)r * N + c) = v;
        } else {
#pragma unroll
            for (int j = 0; j < 4; ++j)
                if (c + j < N)
                    C[(size_t)r * N + c + j] = acc[i][j] * rs + (bias ? bias[c + j] : 0.f);
        }
    }
}

// ---------------------------------------------------------------------------
// in_proj GEMM with SEGMENTED epilogue: output column c routed to dense
// buffers zbuf[.,256] | xbuf[.,256] | bcbuf[.,128] | dtcol[.,4].
// ---------------------------------------------------------------------------
template<int BM, int BN, int BK>
__launch_bounds__(256)
__global__ void gemm_inproj(const float* __restrict__ A, const float* __restrict__ B,
                            int M, int N, int K, int lda,
                            float* __restrict__ zbuf, float* __restrict__ xbuf,
                            float* __restrict__ bcbuf, float* __restrict__ dtcol)
{
    static_assert(BM == 128 && BN == 64 && BK == 16, "tile fixed");
    __shared__ float As[BK][BM + 4];
    __shared__ float Bs[BK][BN];
    const int tid = threadIdx.x;
    const int m0 = blockIdx.y * BM;
    const int n0 = blockIdx.x * BN;
    const int ty = tid >> 4;
    const int tx = tid & 15;

    float acc[8][4];
#pragma unroll
    for (int i = 0; i < 8; ++i)
#pragma unroll
        for (int j = 0; j < 4; ++j) acc[i][j] = 0.f;

    for (int k0 = 0; k0 < K; k0 += BK) {
#pragma unroll
        for (int l = 0; l < 2; ++l) {
            const int idx = tid + l * 256;
            const int r  = idx >> 2;
            const int c4 = (idx & 3) << 2;
            const float4 v = *(const float4*)(A + (size_t)(m0 + r) * lda + k0 + c4);
            As[c4 + 0][r] = v.x; As[c4 + 1][r] = v.y;
            As[c4 + 2][r] = v.z; As[c4 + 3][r] = v.w;
        }
        {
            const int r  = tid >> 4;
            const int c4 = (tid & 15) << 2;
            const int n  = n0 + c4;
            float4 v;
            if (n + 3 < N) {
                v = *(const float4*)(B + (size_t)(k0 + r) * N + n);
            } else {
                v.x = (n + 0) < N ? B[(size_t)(k0 + r) * N + n + 0] : 0.f;
                v.y = (n + 1) < N ? B[(size_t)(k0 + r) * N + n + 1] : 0.f;
                v.z = (n + 2) < N ? B[(size_t)(k0 + r) * N + n + 2] : 0.f;
                v.w = (n + 3) < N ? B[(size_t)(k0 + r) * N + n + 3] : 0.f;
            }
            *(float4*)&Bs[r][c4] = v;
        }
        __syncthreads();
#pragma unroll
        for (int kk = 0; kk < BK; ++kk) {
            const float4 a0 = *(const float4*)&As[kk][ty * 8];
            const float4 a1 = *(const float4*)&As[kk][ty * 8 + 4];
            const float4 b0 = *(const float4*)&Bs[kk][tx * 4];
            const float a[8] = {a0.x, a0.y, a0.z, a0.w, a1.x, a1.y, a1.z, a1.w};
            const float bb[4] = {b0.x, b0.y, b0.z, b0.w};
#pragma unroll
            for (int i = 0; i < 8; ++i)
#pragma unroll
                for (int j = 0; j < 4; ++j)
                    acc[i][j] = fmaf(a[i], bb[j], acc[i][j]);
        }
        __syncthreads();
    }

#pragma unroll
    for (int i = 0; i < 8; ++i) {
        const int r = m0 + ty * 8 + i;
        const int c = n0 + tx * 4;
        const float4 v = make_float4(acc[i][0], acc[i][1], acc[i][2], acc[i][3]);
        if (n0 < 256) {
            *(float4*)(zbuf + (size_t)r * DINNER + c) = v;
        } else if (n0 < 512) {
            *(float4*)(xbuf + (size_t)r * DINNER + (c - 256)) = v;
        } else if (n0 < 640) {
            *(float4*)(bcbuf + (size_t)r * BCW2 + (c - 512)) = v;
        } else {
            if (tx == 0) *(float4*)(dtcol + (size_t)r * 4) = v;  // cols 640..643
        }
    }
}

// ---------------------------------------------------------------------------
__global__ void fuse_whead(const float* __restrict__ W_out, const float* __restrict__ W_act,
                           const float* __restrict__ W_val, const float* __restrict__ norm_w,
                           float* __restrict__ Wh, float* __restrict__ Wv)
{
    const int k = blockIdx.x;
    const int j = threadIdx.x;
    float s = 0.f;
    for (int m = 0; m < DMODEL; ++m)
        s = fmaf(W_out[k * DMODEL + m], W_act[m * NACT + j], s);
    Wh[k * NACT + j] = s * norm_w[k];
    if (j == 0) {
        float sv = 0.f;
        for (int m = 0; m < DMODEL; ++m)
            sv = fmaf(W_out[k * DMODEL + m], W_val[m], sv);
        Wv[k] = sv * norm_w[k];
    }
}

// ---------------------------------------------------------------------------
__global__ void prep_dt(const float* __restrict__ dtcol, const float* __restrict__ dt_bias,
                        const float* __restrict__ A_log,
                        float* __restrict__ dtbuf, float* __restrict__ dAbuf)
{
    const int idx = blockIdx.x * 256 + threadIdx.x;   // tok*4 + h
    if (idx >= NTOK * NHEADS) return;
    const int h = idx & 3;
    const float x = dtcol[idx] + dt_bias[h];
    const float dt = (x > 20.f) ? x : log1pf(expf(x));
    const float A = -expf(A_log[h]);
    dtbuf[idx] = dt;
    dAbuf[idx] = expf(dt * A);
}

// ---------------------------------------------------------------------------
// Chunked selective scan, LDS-FREE. Block = (chunk, batch), 4 waves = 4 heads,
// lane p holds state row s[p][0..63]. Per step: lane n loads raw B[t][n]
// (coalesced), convs it in-register (rolling window, like x), then every lane
// obtains B[n] via v_readlane broadcast (VALU) -- no ds_read, no barriers.
// FINAL=false: phase 1 -> per-chunk states from zero + dA products (B only).
// FINAL=true : phase 3 -> y, g = y*silu(z) written IN PLACE into zbuf.
//   (rms/value reduction moved to rms_val kernel.)
// ---------------------------------------------------------------------------
template<bool FINAL>
__launch_bounds__(256)
__global__ void scan_kernel(const float* __restrict__ xbuf,   // [tok][256]
                            const float* __restrict__ bcbuf,  // [tok][128]
                            float* zbuf,                      // [tok][256] z -> g in place
                            const float* __restrict__ dtbuf,
                            const float* __restrict__ dAbuf,
                            const float* __restrict__ W_conv,
                            const float* __restrict__ b_conv,
                            const float* __restrict__ Dparam,
                            float* __restrict__ states,   // [b*4+h][chunk][64][64]
                            float* __restrict__ dAprod)   // [b*4+h][chunk]
{
    const int b   = blockIdx.y;
    const int ch  = blockIdx.x;
    const int tid = threadIdx.x;
    const int h = tid >> 6;
    const int p = tid & 63;

    const int xch = h * HEADDIM + p;
    // conv weights: x channel (xch), B channel (p), C channel (64+p)
    const float wx0 = W_conv[xch * 4 + 0], wx1 = W_conv[xch * 4 + 1];
    const float wx2 = W_conv[xch * 4 + 2], wx3 = W_conv[xch * 4 + 3];
    const float bx  = b_conv[xch];
    const float wB0 = W_conv[(DINNER + p) * 4 + 0], wB1 = W_conv[(DINNER + p) * 4 + 1];
    const float wB2 = W_conv[(DINNER + p) * 4 + 2], wB3 = W_conv[(DINNER + p) * 4 + 3];
    const float bB  = b_conv[DINNER + p];
    const float wC0 = FINAL ? W_conv[(DINNER + 64 + p) * 4 + 0] : 0.f;
    const float wC1 = FINAL ? W_conv[(DINNER + 64 + p) * 4 + 1] : 0.f;
    const float wC2 = FINAL ? W_conv[(DINNER + 64 + p) * 4 + 2] : 0.f;
    const float wC3 = FINAL ? W_conv[(DINNER + 64 + p) * 4 + 3] : 0.f;
    const float bC  = FINAL ? b_conv[DINNER + 64 + p] : 0.f;
    const float Dh = Dparam[h];

    const size_t row0 = (size_t)b * TSEQ;
    const int tbase = ch * CHUNK;

    float s[64];
    const int bh = b * NHEADS + h;
    const size_t stoff = (((size_t)bh * NCHUNK + ch) * 64 + p) * 64;
    if constexpr (FINAL) {
#pragma unroll
        for (int n4 = 0; n4 < 16; ++n4) {
            const float4 v = *(const float4*)(states + stoff + n4 * 4);
            s[n4 * 4 + 0] = v.x; s[n4 * 4 + 1] = v.y; s[n4 * 4 + 2] = v.z; s[n4 * 4 + 3] = v.w;
        }
    } else {
#pragma unroll
        for (int n = 0; n < 64; ++n) s[n] = 0.f;
    }

    // rolling raw windows (t-3, t-2, t-1) for x, B, C (zero-padded at seq start)
    float xw0 = 0.f, xw1 = 0.f, xw2 = 0.f;
    float Bw0 = 0.f, Bw1 = 0.f, Bw2 = 0.f;
    float Cw0 = 0.f, Cw1 = 0.f, Cw2 = 0.f;
    if (tbase >= 1) {
        xw2 = xbuf[(row0 + tbase - 1) * DINNER + xch];
        Bw2 = bcbuf[(row0 + tbase - 1) * BCW2 + p];
        if (FINAL) Cw2 = bcbuf[(row0 + tbase - 1) * BCW2 + 64 + p];
    }
    if (tbase >= 2) {
        xw1 = xbuf[(row0 + tbase - 2) * DINNER + xch];
        Bw1 = bcbuf[(row0 + tbase - 2) * BCW2 + p];
        if (FINAL) Cw1 = bcbuf[(row0 + tbase - 2) * BCW2 + 64 + p];
    }
    if (tbase >= 3) {
        xw0 = xbuf[(row0 + tbase - 3) * DINNER + xch];
        Bw0 = bcbuf[(row0 + tbase - 3) * BCW2 + p];
        if (FINAL) Cw0 = bcbuf[(row0 + tbase - 3) * BCW2 + 64 + p];
    }

    float dAp = 1.f;

#pragma unroll 2
    for (int tt = 0; tt < CHUNK; ++tt) {
        const int t = tbase + tt;
        const size_t tok = row0 + t;
        const float dt = dtbuf[tok * NHEADS + h];
        const float dA = dAbuf[tok * NHEADS + h];
        const float xn = xbuf[tok * DINNER + xch];
        const float Bn = bcbuf[tok * BCW2 + p];

        float xc = siluf(fmaf(xn, wx3, fmaf(xw2, wx2, fmaf(xw1, wx1, fmaf(xw0, wx0, bx)))));
        xw0 = xw1; xw1 = xw2; xw2 = xn;
        const float Bc = siluf(fmaf(Bn, wB3, fmaf(Bw2, wB2, fmaf(Bw1, wB1, fmaf(Bw0, wB0, bB)))));
        Bw0 = Bw1; Bw1 = Bw2; Bw2 = Bn;
        const float dtx = dt * xc;

        if constexpr (!FINAL) {
            dAp *= dA;
#pragma unroll
            for (int n = 0; n < 64; ++n)
                s[n] = fmaf(dA, s[n], dtx * rdlane(Bc, n));
        } else {
            const float Cn = bcbuf[tok * BCW2 + 64 + p];
            const float Cc = siluf(fmaf(Cn, wC3, fmaf(Cw2, wC2, fmaf(Cw1, wC1, fmaf(Cw0, wC0, bC)))));
            Cw0 = Cw1; Cw1 = Cw2; Cw2 = Cn;
            float y0 = 0.f, y1 = 0.f, y2 = 0.f, y3 = 0.f;
#pragma unroll
            for (int n = 0; n < 64; n += 4) {
                const float s0_ = fmaf(dA, s[n + 0], dtx * rdlane(Bc, n + 0)); s[n + 0] = s0_;
                const float s1_ = fmaf(dA, s[n + 1], dtx * rdlane(Bc, n + 1)); s[n + 1] = s1_;
                const float s2_ = fmaf(dA, s[n + 2], dtx * rdlane(Bc, n + 2)); s[n + 2] = s2_;
                const float s3_ = fmaf(dA, s[n + 3], dtx * rdlane(Bc, n + 3)); s[n + 3] = s3_;
                y0 = fmaf(s0_, rdlane(Cc, n + 0), y0);
                y1 = fmaf(s1_, rdlane(Cc, n + 1), y1);
                y2 = fmaf(s2_, rdlane(Cc, n + 2), y2);
                y3 = fmaf(s3_, rdlane(Cc, n + 3), y3);
            }
            const float y = (y0 + y1) + (y2 + y3) + Dh * xc;
            const float z = zbuf[tok * DINNER + xch];
            zbuf[tok * DINNER + xch] = y * siluf(z);   // overwrite z slot (read above)
        }
    }

    if constexpr (!FINAL) {
#pragma unroll
        for (int n4 = 0; n4 < 16; ++n4)
            *(float4*)(states + stoff + n4 * 4) =
                make_float4(s[n4 * 4 + 0], s[n4 * 4 + 1], s[n4 * 4 + 2], s[n4 * 4 + 3]);
        if (p == 0) dAprod[bh * NCHUNK + ch] = dAp;
    }
}

// ---------------------------------------------------------------------------
// Per-token RMS + value head from g (one wave per token, 4 tokens per block).
// ---------------------------------------------------------------------------
__launch_bounds__(256)
__global__ void rms_val(const float* __restrict__ g, const float* __restrict__ Wv,
                        const float* __restrict__ bval,
                        float* __restrict__ rmsbuf, float* __restrict__ values)
{
    const size_t tok = (size_t)blockIdx.x * 4 + (threadIdx.x >> 6);
    const int lane = threadIdx.x & 63;
    const float4 v = *(const float4*)(g + tok * DINNER + lane * 4);
    const float4 w = *(const float4*)(Wv + lane * 4);
    float ssq = v.x * v.x + v.y * v.y + v.z * v.z + v.w * v.w;
    float gw  = v.x * w.x + v.y * w.y + v.z * w.z + v.w * w.w;
#pragma unroll
    for (int d = 1; d < 64; d <<= 1) {
        ssq += __shfl_xor(ssq, d, 64);
        gw  += __shfl_xor(gw, d, 64);
    }
    if (lane == 0) {
        const float rms = rsqrtf(ssq * (1.f / DINNER) + 1e-5f);
        rmsbuf[tok] = rms;
        values[tok] = gw * rms + bval[0];
    }
}

// ---------------------------------------------------------------------------
// Inter-chunk state recurrence (in place): one thread per (bh, state element).
// ---------------------------------------------------------------------------
__global__ void chunk_scan(float* __restrict__ states, const float* __restrict__ dAprod)
{
    __shared__ float sdA[NCHUNK];
    const int bh = blockIdx.x >> 4;                       // 16 blocks per bh
    const int elem = ((blockIdx.x & 15) << 8) | threadIdx.x;
    if (threadIdx.x < NCHUNK) sdA[threadIdx.x] = dAprod[bh * NCHUNK + threadIdx.x];
    __syncthreads();
    const size_t base = (size_t)bh * NCHUNK * 4096 + elem;
    float s0 = 0.f;
    for (int c = 0; c < NCHUNK; ++c) {
        const size_t off = base + (size_t)c * 4096;
        const float Sc = states[off];
        states[off] = s0;
        s0 = fmaf(sdA[c], s0, Sc);
    }
}

// ---------------------------------------------------------------------------
extern "C" void kernel_launch(void* const* d_in, const int* in_sizes, int n_in,
                              void* d_out, int out_size, void* d_ws, size_t ws_size,
                              hipStream_t stream)
{
    (void)in_sizes; (void)n_in; (void)out_size; (void)ws_size;
    const float* obs     = (const float*)d_in[0];
    const float* W_enc   = (const float*)d_in[1];
    const float* b_enc   = (const float*)d_in[2];
    const float* W_in    = (const float*)d_in[3];
    const float* W_conv  = (const float*)d_in[4];
    const float* b_conv  = (const float*)d_in[5];
    const float* dt_bias = (const float*)d_in[6];
    const float* A_log   = (const float*)d_in[7];
    const float* Dp      = (const float*)d_in[8];
    const float* norm_w  = (const float*)d_in[9];
    const float* W_out   = (const float*)d_in[10];
    const float* W_act   = (const float*)d_in[11];
    const float* b_act   = (const float*)d_in[12];
    const float* W_val   = (const float*)d_in[13];
    const float* b_val   = (const float*)d_in[14];

    float* logits = (float*)d_out;
    float* values = logits + (size_t)NTOK * NACT;

    char* ws = (char*)d_ws;
    size_t off = 0;
    auto alloc = [&](size_t nfloats) {
        float* ptr = (float*)(ws + off);
        off += ((nfloats * 4 + 255) / 256) * 256;
        return ptr;
    };
    // ws high-water: 134.2+134.2+67.1+2.1 +67.1+67.1 + ~5 = ~477 MB
    float* zbuf   = alloc((size_t)NTOK * DINNER);                   // 134.2 MB (z -> g)
    float* xbuf   = alloc((size_t)NTOK * DINNER);                   // 134.2 MB
    float* bcbuf  = alloc((size_t)NTOK * BCW2);                     //  67.1 MB
    float* dtcol  = alloc((size_t)NTOK * 4);                        //   2.1 MB
    float* hidden = alloc((size_t)NTOK * DMODEL);                   //  67.1 MB
    float* states = alloc((size_t)NBATCH * NHEADS * NCHUNK * 4096); //  67.1 MB
    float* dAp    = alloc(NBATCH * NHEADS * NCHUNK);
    float* dtbuf  = alloc((size_t)NTOK * NHEADS);
    float* dAbuf  = alloc((size_t)NTOK * NHEADS);
    float* rmsbuf = alloc(NTOK);
    float* Wh     = alloc(DINNER * NACT);
    float* Wv     = alloc(DINNER);

    // 1. fused head weights
    fuse_whead<<<DINNER, NACT, 0, stream>>>(W_out, W_act, W_val, norm_w, Wh, Wv);
    // 2. hidden = obs @ W_enc + b_enc
    gemm_rrr<128, 64, 16><<<dim3(DMODEL / 64, NTOK / 128), 256, 0, stream>>>(
        obs, W_enc, hidden, NTOK, DMODEL, OBSD, OBSD, b_enc, nullptr);
    // 3. segmented in_proj: hidden @ W_in -> zbuf | xbuf | bcbuf | dtcol
    gemm_inproj<128, 64, 16><<<dim3((NPROJ + 63) / 64, NTOK / 128), 256, 0, stream>>>(
        hidden, W_in, NTOK, NPROJ, DMODEL, DMODEL, zbuf, xbuf, bcbuf, dtcol);
    // 4. dt / dA
    prep_dt<<<(NTOK * NHEADS + 255) / 256, 256, 0, stream>>>(dtcol, dt_bias, A_log, dtbuf, dAbuf);
    // 5. phase 1: chunk states (no LDS, readlane broadcast)
    scan_kernel<false><<<dim3(NCHUNK, NBATCH), 256, 0, stream>>>(
        xbuf, bcbuf, zbuf, dtbuf, dAbuf, W_conv, b_conv, Dp, states, dAp);
    // 6. phase 2: inter-chunk recurrence
    chunk_scan<<<NBATCH * NHEADS * 16, 256, 0, stream>>>(states, dAp);
    // 7. phase 3: outputs (g -> zbuf in place)
    scan_kernel<true><<<dim3(NCHUNK, NBATCH), 256, 0, stream>>>(
        xbuf, bcbuf, zbuf, dtbuf, dAbuf, W_conv, b_conv, Dp, states, dAp);
    // 8. per-token rms + value head
    rms_val<<<NTOK / 4, 256, 0, stream>>>(zbuf, Wv, b_val, rmsbuf, values);
    // 9. logits = rms * (g @ Wh) + b_act   (A = zbuf dense, lda = 256)
    gemm_rrr<128, 64, 16><<<dim3(1, NTOK / 128), 256, 0, stream>>>(
        zbuf, Wh, logits, NTOK, NACT, DINNER, DINNER, b_act, rmsbuf);
}

// Round 9
// 1016.664 us; speedup vs baseline: 1.1565x; 1.1565x over previous
//
#include <hip/hip_runtime.h>
#include <math.h>

#define OBSD   256
#define TSEQ   4096
#define NBATCH 32
#define DMODEL 128
#define DSTATE 64
#define DINNER 256
#define NHEADS 4
#define HEADDIM 64
#define NPROJ  644
#define NTOK   (NBATCH*TSEQ)
#define CHUNK  64
#define NCHUNK (TSEQ/CHUNK)
#define NACT   64
#define BCW2   128   // bcbuf row width (B 64 | C 64)
#define LP     68    // padded LDS row stride

__device__ __forceinline__ float siluf(float x) { return x / (1.f + __expf(-x)); }

// ---------------------------------------------------------------------------
// fp32 tiled GEMM (unchanged from round 5): A(MxK) lda, B(KxN), C(MxN).
// C = (A@B) * rowscale[r] + bias[c]
// ---------------------------------------------------------------------------
template<int BM, int BN, int BK>
__launch_bounds__(256)
__global__ void gemm_rrr(const float* __restrict__ A, const float* __restrict__ B,
                         float* __restrict__ C, int M, int N, int K, int lda,
                         const float* __restrict__ bias, const float* __restrict__ rowscale)
{
    static_assert(BM == 128 && BN == 64 && BK == 16, "tile fixed");
    __shared__ float As[BK][BM + 4];
    __shared__ float Bs[BK][BN];
    const int tid = threadIdx.x;
    const int m0 = blockIdx.y * BM;
    const int n0 = blockIdx.x * BN;
    const int ty = tid >> 4;
    const int tx = tid & 15;

    float acc[8][4];
#pragma unroll
    for (int i = 0; i < 8; ++i)
#pragma unroll
        for (int j = 0; j < 4; ++j) acc[i][j] = 0.f;

    for (int k0 = 0; k0 < K; k0 += BK) {
#pragma unroll
        for (int l = 0; l < 2; ++l) {
            const int idx = tid + l * 256;
            const int r  = idx >> 2;
            const int c4 = (idx & 3) << 2;
            const float4 v = *(const float4*)(A + (size_t)(m0 + r) * lda + k0 + c4);
            As[c4 + 0][r] = v.x; As[c4 + 1][r] = v.y;
            As[c4 + 2][r] = v.z; As[c4 + 3][r] = v.w;
        }
        {
            const int r  = tid >> 4;
            const int c4 = (tid & 15) << 2;
            const int n  = n0 + c4;
            float4 v;
            if (n + 3 < N) {
                v = *(const float4*)(B + (size_t)(k0 + r) * N + n);
            } else {
                v.x = (n + 0) < N ? B[(size_t)(k0 + r) * N + n + 0] : 0.f;
                v.y = (n + 1) < N ? B[(size_t)(k0 + r) * N + n + 1] : 0.f;
                v.z = (n + 2) < N ? B[(size_t)(k0 + r) * N + n + 2] : 0.f;
                v.w = (n + 3) < N ? B[(size_t)(k0 + r) * N + n + 3] : 0.f;
            }
            *(float4*)&Bs[r][c4] = v;
        }
        __syncthreads();
#pragma unroll
        for (int kk = 0; kk < BK; ++kk) {
            const float4 a0 = *(const float4*)&As[kk][ty * 8];
            const float4 a1 = *(const float4*)&As[kk][ty * 8 + 4];
            const float4 b0 = *(const float4*)&Bs[kk][tx * 4];
            const float a[8] = {a0.x, a0.y, a0.z, a0.w, a1.x, a1.y, a1.z, a1.w};
            const float bb[4] = {b0.x, b0.y, b0.z, b0.w};
#pragma unroll
            for (int i = 0; i < 8; ++i)
#pragma unroll
                for (int j = 0; j < 4; ++j)
                    acc[i][j] = fmaf(a[i], bb[j], acc[i][j]);
        }
        __syncthreads();
    }

#pragma unroll
    for (int i = 0; i < 8; ++i) {
        const int r = m0 + ty * 8 + i;
        const float rs = rowscale ? rowscale[r] : 1.f;
        const int c = n0 + tx * 4;
        if (c + 3 < N) {
            float4 v;
            v.x = acc[i][0] * rs + (bias ? bias[c + 0] : 0.f);
            v.y = acc[i][1] * rs + (bias ? bias[c + 1] : 0.f);
            v.z = acc[i][2] * rs + (bias ? bias[c + 2] : 0.f);
            v.w = acc[i][3] * rs + (bias ? bias[c + 3] : 0.f);
            *(float4*)(C + (size_t)r * N + c) = v;
        } else {
#pragma unroll
            for (int j = 0; j < 4; ++j)
                if (c + j < N)
                    C[(size_t)r * N + c + j] = acc[i][j] * rs + (bias ? bias[c + j] : 0.f);
        }
    }
}

// ---------------------------------------------------------------------------
// in_proj GEMM with SEGMENTED epilogue (unchanged from round 5).
// ---------------------------------------------------------------------------
template<int BM, int BN, int BK>
__launch_bounds__(256)
__global__ void gemm_inproj(const float* __restrict__ A, const float* __restrict__ B,
                            int M, int N, int K, int lda,
                            float* __restrict__ zbuf, float* __restrict__ xbuf,
                            float* __restrict__ bcbuf, float* __restrict__ dtcol)
{
    static_assert(BM == 128 && BN == 64 && BK == 16, "tile fixed");
    __shared__ float As[BK][BM + 4];
    __shared__ float Bs[BK][BN];
    const int tid = threadIdx.x;
    const int m0 = blockIdx.y * BM;
    const int n0 = blockIdx.x * BN;
    const int ty = tid >> 4;
    const int tx = tid & 15;

    float acc[8][4];
#pragma unroll
    for (int i = 0; i < 8; ++i)
#pragma unroll
        for (int j = 0; j < 4; ++j) acc[i][j] = 0.f;

    for (int k0 = 0; k0 < K; k0 += BK) {
#pragma unroll
        for (int l = 0; l < 2; ++l) {
            const int idx = tid + l * 256;
            const int r  = idx >> 2;
            const int c4 = (idx & 3) << 2;
            const float4 v = *(const float4*)(A + (size_t)(m0 + r) * lda + k0 + c4);
            As[c4 + 0][r] = v.x; As[c4 + 1][r] = v.y;
            As[c4 + 2][r] = v.z; As[c4 + 3][r] = v.w;
        }
        {
            const int r  = tid >> 4;
            const int c4 = (tid & 15) << 2;
            const int n  = n0 + c4;
            float4 v;
            if (n + 3 < N) {
                v = *(const float4*)(B + (size_t)(k0 + r) * N + n);
            } else {
                v.x = (n + 0) < N ? B[(size_t)(k0 + r) * N + n + 0] : 0.f;
                v.y = (n + 1) < N ? B[(size_t)(k0 + r) * N + n + 1] : 0.f;
                v.z = (n + 2) < N ? B[(size_t)(k0 + r) * N + n + 2] : 0.f;
                v.w = (n + 3) < N ? B[(size_t)(k0 + r) * N + n + 3] : 0.f;
            }
            *(float4*)&Bs[r][c4] = v;
        }
        __syncthreads();
#pragma unroll
        for (int kk = 0; kk < BK; ++kk) {
            const float4 a0 = *(const float4*)&As[kk][ty * 8];
            const float4 a1 = *(const float4*)&As[kk][ty * 8 + 4];
            const float4 b0 = *(const float4*)&Bs[kk][tx * 4];
            const float a[8] = {a0.x, a0.y, a0.z, a0.w, a1.x, a1.y, a1.z, a1.w};
            const float bb[4] = {b0.x, b0.y, b0.z, b0.w};
#pragma unroll
            for (int i = 0; i < 8; ++i)
#pragma unroll
                for (int j = 0; j < 4; ++j)
                    acc[i][j] = fmaf(a[i], bb[j], acc[i][j]);
        }
        __syncthreads();
    }

#pragma unroll
    for (int i = 0; i < 8; ++i) {
        const int r = m0 + ty * 8 + i;
        const int c = n0 + tx * 4;
        const float4 v = make_float4(acc[i][0], acc[i][1], acc[i][2], acc[i][3]);
        if (n0 < 256) {
            *(float4*)(zbuf + (size_t)r * DINNER + c) = v;
        } else if (n0 < 512) {
            *(float4*)(xbuf + (size_t)r * DINNER + (c - 256)) = v;
        } else if (n0 < 640) {
            *(float4*)(bcbuf + (size_t)r * BCW2 + (c - 512)) = v;
        } else {
            if (tx == 0) *(float4*)(dtcol + (size_t)r * 4) = v;
        }
    }
}

// ---------------------------------------------------------------------------
__global__ void fuse_whead(const float* __restrict__ W_out, const float* __restrict__ W_act,
                           const float* __restrict__ W_val, const float* __restrict__ norm_w,
                           float* __restrict__ Wh, float* __restrict__ Wv)
{
    const int k = blockIdx.x;
    const int j = threadIdx.x;
    float s = 0.f;
    for (int m = 0; m < DMODEL; ++m)
        s = fmaf(W_out[k * DMODEL + m], W_act[m * NACT + j], s);
    Wh[k * NACT + j] = s * norm_w[k];
    if (j == 0) {
        float sv = 0.f;
        for (int m = 0; m < DMODEL; ++m)
            sv = fmaf(W_out[k * DMODEL + m], W_val[m], sv);
        Wv[k] = sv * norm_w[k];
    }
}

// ---------------------------------------------------------------------------
// prep: per (bh, chunk): dt = softplus, la = inclusive cumsum(dt*A) within
// chunk (wave scan), dAp = exp(la[63]). Layouts dtT/laT = [bh][4096].
// ---------------------------------------------------------------------------
__global__ void prep_scan(const float* __restrict__ dtcol, const float* __restrict__ dt_bias,
                          const float* __restrict__ A_log,
                          float* __restrict__ dtT, float* __restrict__ laT,
                          float* __restrict__ dApbuf)
{
    const int bc = blockIdx.x;              // bh*NCHUNK + c
    const int bh = bc >> 6, c = bc & 63;
    const int b = bh >> 2, h = bh & 3;
    const int lane = threadIdx.x;           // 64 threads
    const size_t tok = (size_t)b * TSEQ + c * CHUNK + lane;
    const float x = dtcol[tok * 4 + h] + dt_bias[h];
    const float dt = (x > 20.f) ? x : log1pf(expf(x));
    const float A = -expf(A_log[h]);
    float v = dt * A;
#pragma unroll
    for (int d = 1; d < 64; d <<= 1) {
        const float o = __shfl_up(v, d, 64);
        if (lane >= d) v += o;
    }
    const size_t o = (size_t)bh * TSEQ + c * CHUNK + lane;
    dtT[o] = dt;
    laT[o] = v;
    if (lane == 63) dApbuf[bh * NCHUNK + c] = __expf(v);
}

// ---------------------------------------------------------------------------
// Phase A: chunk-local states via GEMM.  S_c[p][n] = sum_i w_i X[i][p] B[i][n],
// w_i = dt_i * exp(la_63 - la_i).  Conv+silu fused in staging.
// Block = (chunk c, bh). 256 threads, 16 outputs each.
// ---------------------------------------------------------------------------
__launch_bounds__(256)
__global__ void scan_state(const float* __restrict__ xbuf, const float* __restrict__ bcbuf,
                           const float* __restrict__ dtT, const float* __restrict__ laT,
                           const float* __restrict__ W_conv, const float* __restrict__ b_conv,
                           float* __restrict__ states)
{
    __shared__ float Xs[CHUNK][LP];
    __shared__ float Bw[CHUNK][LP];
    __shared__ float w_l[CHUNK];
    const int c = blockIdx.x, bh = blockIdx.y;
    const int b = bh >> 2, h = bh & 3;
    const int tid = threadIdx.x;
    const size_t row0 = (size_t)b * TSEQ;
    const int tb = c * CHUNK;

    if (tid < CHUNK) {
        const size_t o = (size_t)bh * TSEQ + tb;
        const float laLast = laT[o + CHUNK - 1];
        w_l[tid] = dtT[o + tid] * __expf(laLast - laT[o + tid]);
    }
    __syncthreads();

    const int sg = tid & 15, st = tid >> 4;
    const int t4 = st * 4;

    // ---- Xs: conv+silu of x, this head's 64 channels ----
    {
        const int ch = h * HEADDIM + sg * 4;
        float w[4][4], bb[4];
#pragma unroll
        for (int j = 0; j < 4; ++j) {
            bb[j] = b_conv[ch + j];
#pragma unroll
            for (int k = 0; k < 4; ++k) w[j][k] = W_conv[(ch + j) * 4 + k];
        }
        float rx[4][7];
#pragma unroll
        for (int r = 0; r < 7; ++r) {
            const int tg = tb + t4 - 3 + r;
            float4 v = make_float4(0.f, 0.f, 0.f, 0.f);
            if (tg >= 0) v = *(const float4*)(xbuf + (row0 + tg) * DINNER + ch);
            rx[0][r] = v.x; rx[1][r] = v.y; rx[2][r] = v.z; rx[3][r] = v.w;
        }
#pragma unroll
        for (int i = 0; i < 4; ++i) {
            float o[4];
#pragma unroll
            for (int j = 0; j < 4; ++j)
                o[j] = siluf(fmaf(rx[j][i + 3], w[j][3], fmaf(rx[j][i + 2], w[j][2],
                             fmaf(rx[j][i + 1], w[j][1], fmaf(rx[j][i], w[j][0], bb[j])))));
            *(float4*)&Xs[t4 + i][sg * 4] = make_float4(o[0], o[1], o[2], o[3]);
        }
    }
    // ---- Bw: conv+silu of B, scaled by w_i ----
    {
        const int ch = sg * 4;   // B channels 0..63 of bcbuf
        float w[4][4], bb[4];
#pragma unroll
        for (int j = 0; j < 4; ++j) {
            bb[j] = b_conv[DINNER + ch + j];
#pragma unroll
            for (int k = 0; k < 4; ++k) w[j][k] = W_conv[(DINNER + ch + j) * 4 + k];
        }
        float rx[4][7];
#pragma unroll
        for (int r = 0; r < 7; ++r) {
            const int tg = tb + t4 - 3 + r;
            float4 v = make_float4(0.f, 0.f, 0.f, 0.f);
            if (tg >= 0) v = *(const float4*)(bcbuf + (row0 + tg) * BCW2 + ch);
            rx[0][r] = v.x; rx[1][r] = v.y; rx[2][r] = v.z; rx[3][r] = v.w;
        }
#pragma unroll
        for (int i = 0; i < 4; ++i) {
            const float wi = w_l[t4 + i];
            float o[4];
#pragma unroll
            for (int j = 0; j < 4; ++j)
                o[j] = wi * siluf(fmaf(rx[j][i + 3], w[j][3], fmaf(rx[j][i + 2], w[j][2],
                              fmaf(rx[j][i + 1], w[j][1], fmaf(rx[j][i], w[j][0], bb[j])))));
            *(float4*)&Bw[t4 + i][sg * 4] = make_float4(o[0], o[1], o[2], o[3]);
        }
    }
    __syncthreads();

    // ---- GEMM: S[p][n] = sum_i Xs[i][p] * Bw[i][n] ----
    const int pn = tid & 15, pp = tid >> 4;
    const int n4 = pn * 4, p4 = pp * 4;
    float acc[4][4];
#pragma unroll
    for (int a = 0; a < 4; ++a)
#pragma unroll
        for (int d = 0; d < 4; ++d) acc[a][d] = 0.f;
#pragma unroll 4
    for (int i = 0; i < CHUNK; ++i) {
        const float4 xv = *(const float4*)&Xs[i][p4];   // broadcast within pp-group
        const float4 bv = *(const float4*)&Bw[i][n4];
        const float xa[4] = {xv.x, xv.y, xv.z, xv.w};
        const float ba[4] = {bv.x, bv.y, bv.z, bv.w};
#pragma unroll
        for (int a = 0; a < 4; ++a)
#pragma unroll
            for (int d = 0; d < 4; ++d) acc[a][d] = fmaf(xa[a], ba[d], acc[a][d]);
    }
    const size_t so = (size_t)(bh * NCHUNK + c) * 4096;
#pragma unroll
    for (int a = 0; a < 4; ++a)
        *(float4*)(states + so + (size_t)(p4 + a) * 64 + n4) =
            make_float4(acc[a][0], acc[a][1], acc[a][2], acc[a][3]);
}

// ---------------------------------------------------------------------------
// Inter-chunk recurrence (in place). states[bh][c] -> INITIAL state of chunk c.
// ---------------------------------------------------------------------------
__global__ void chunk_scan(float* __restrict__ states, const float* __restrict__ dAprod)
{
    __shared__ float sdA[NCHUNK];
    const int bh = blockIdx.x >> 4;
    const int elem = ((blockIdx.x & 15) << 8) | threadIdx.x;
    if (threadIdx.x < NCHUNK) sdA[threadIdx.x] = dAprod[bh * NCHUNK + threadIdx.x];
    __syncthreads();
    const size_t base = (size_t)bh * NCHUNK * 4096 + elem;
    float s0 = 0.f;
    for (int c = 0; c < NCHUNK; ++c) {
        const size_t off = base + (size_t)c * 4096;
        const float Sc = states[off];
        states[off] = s0;
        s0 = fmaf(sdA[c], s0, Sc);
    }
}

// ---------------------------------------------------------------------------
// Phase B: outputs via 3 micro-GEMMs per (bh, chunk).
//   M[t][i] = (C_t.B_i) * dt_i * exp(la_t - la_i)  (i<=t, masked BEFORE exp)
//   Y = M@X + diag(exp(la)) * (C @ S_old^T) + D*X ;  g = Y*silu(z) -> zbuf
// LDS: BcT/CcT/Xs [64][68] (~52 KB); ST reuses BcT, MT reuses CcT.
// ---------------------------------------------------------------------------
__launch_bounds__(256)
__global__ void scan_out(const float* __restrict__ xbuf, const float* __restrict__ bcbuf,
                         float* zbuf,
                         const float* __restrict__ dtT, const float* __restrict__ laT,
                         const float* __restrict__ W_conv, const float* __restrict__ b_conv,
                         const float* __restrict__ Dparam,
                         const float* __restrict__ states)
{
    __shared__ float BcT[CHUNK][LP];   // [n][i] ; later ST[n][p]
    __shared__ float CcT[CHUNK][LP];   // [n][t] ; later MT[i][t]
    __shared__ float Xs[CHUNK][LP];    // [i][p]
    __shared__ float la_l[CHUNK], dt_l[CHUNK], a_l[CHUNK];
    float (*ST)[LP] = BcT;
    float (*MT)[LP] = CcT;

    const int c = blockIdx.x, bh = blockIdx.y;
    const int b = bh >> 2, h = bh & 3;
    const int tid = threadIdx.x;
    const size_t row0 = (size_t)b * TSEQ;
    const int tb = c * CHUNK;
    const float Dh = Dparam[h];

    // issue S_old loads early (consumed after GEMM1)
    const int pS = tid >> 2;
    const int n16 = (tid & 3) * 16;
    const float* Sg = states + (size_t)(bh * NCHUNK + c) * 4096 + (size_t)pS * 64 + n16;
    const float4 sv0 = *(const float4*)(Sg + 0);
    const float4 sv1 = *(const float4*)(Sg + 4);
    const float4 sv2 = *(const float4*)(Sg + 8);
    const float4 sv3 = *(const float4*)(Sg + 12);

    if (tid < CHUNK) {
        const size_t o = (size_t)bh * TSEQ + tb + tid;
        const float la = laT[o];
        la_l[tid] = la;
        dt_l[tid] = dtT[o];
        a_l[tid] = __expf(la);
    }

    const int sg = tid & 15, st = tid >> 4;
    const int t4s = st * 4;

    // ---- Xs[i][p]: conv+silu x (head channels) ----
    {
        const int ch = h * HEADDIM + sg * 4;
        float w[4][4], bb[4];
#pragma unroll
        for (int j = 0; j < 4; ++j) {
            bb[j] = b_conv[ch + j];
#pragma unroll
            for (int k = 0; k < 4; ++k) w[j][k] = W_conv[(ch + j) * 4 + k];
        }
        float rx[4][7];
#pragma unroll
        for (int r = 0; r < 7; ++r) {
            const int tg = tb + t4s - 3 + r;
            float4 v = make_float4(0.f, 0.f, 0.f, 0.f);
            if (tg >= 0) v = *(const float4*)(xbuf + (row0 + tg) * DINNER + ch);
            rx[0][r] = v.x; rx[1][r] = v.y; rx[2][r] = v.z; rx[3][r] = v.w;
        }
#pragma unroll
        for (int i = 0; i < 4; ++i) {
            float o[4];
#pragma unroll
            for (int j = 0; j < 4; ++j)
                o[j] = siluf(fmaf(rx[j][i + 3], w[j][3], fmaf(rx[j][i + 2], w[j][2],
                             fmaf(rx[j][i + 1], w[j][1], fmaf(rx[j][i], w[j][0], bb[j])))));
            *(float4*)&Xs[t4s + i][sg * 4] = make_float4(o[0], o[1], o[2], o[3]);
        }
    }
    // ---- BcT[n][i]: conv+silu B, TRANSPOSED store ----
    {
        const int ch = sg * 4;
        float w[4][4], bb[4];
#pragma unroll
        for (int j = 0; j < 4; ++j) {
            bb[j] = b_conv[DINNER + ch + j];
#pragma unroll
            for (int k = 0; k < 4; ++k) w[j][k] = W_conv[(DINNER + ch + j) * 4 + k];
        }
        float rx[4][7];
#pragma unroll
        for (int r = 0; r < 7; ++r) {
            const int tg = tb + t4s - 3 + r;
            float4 v = make_float4(0.f, 0.f, 0.f, 0.f);
            if (tg >= 0) v = *(const float4*)(bcbuf + (row0 + tg) * BCW2 + ch);
            rx[0][r] = v.x; rx[1][r] = v.y; rx[2][r] = v.z; rx[3][r] = v.w;
        }
#pragma unroll
        for (int j = 0; j < 4; ++j) {
            float o[4];
#pragma unroll
            for (int i = 0; i < 4; ++i)
                o[i] = siluf(fmaf(rx[j][i + 3], w[j][3], fmaf(rx[j][i + 2], w[j][2],
                             fmaf(rx[j][i + 1], w[j][1], fmaf(rx[j][i], w[j][0], bb[j])))));
            *(float4*)&BcT[ch + j][t4s] = make_float4(o[0], o[1], o[2], o[3]);
        }
    }
    // ---- CcT[n][t]: conv+silu C, TRANSPOSED store ----
    {
        const int ch = sg * 4;
        float w[4][4], bb[4];
#pragma unroll
        for (int j = 0; j < 4; ++j) {
            bb[j] = b_conv[DINNER + 64 + ch + j];
#pragma unroll
            for (int k = 0; k < 4; ++k) w[j][k] = W_conv[(DINNER + 64 + ch + j) * 4 + k];
        }
        float rx[4][7];
#pragma unroll
        for (int r = 0; r < 7; ++r) {
            const int tg = tb + t4s - 3 + r;
            float4 v = make_float4(0.f, 0.f, 0.f, 0.f);
            if (tg >= 0) v = *(const float4*)(bcbuf + (row0 + tg) * BCW2 + 64 + ch);
            rx[0][r] = v.x; rx[1][r] = v.y; rx[2][r] = v.z; rx[3][r] = v.w;
        }
#pragma unroll
        for (int j = 0; j < 4; ++j) {
            float o[4];
#pragma unroll
            for (int i = 0; i < 4; ++i)
                o[i] = siluf(fmaf(rx[j][i + 3], w[j][3], fmaf(rx[j][i + 2], w[j][2],
                             fmaf(rx[j][i + 1], w[j][1], fmaf(rx[j][i], w[j][0], bb[j])))));
            *(float4*)&CcT[ch + j][t4s] = make_float4(o[0], o[1], o[2], o[3]);
        }
    }
    __syncthreads();

    const int ti = tid & 15, tt = tid >> 4;
    const int i4 = ti * 4, t4 = tt * 4;   // i4 doubles as p4 for GEMM2/3

    // ---- GEMM1: m[a][b] = sum_n CcT[n][t4+a] * BcT[n][i4+b] ----
    float m[4][4];
#pragma unroll
    for (int a = 0; a < 4; ++a)
#pragma unroll
        for (int d = 0; d < 4; ++d) m[a][d] = 0.f;
#pragma unroll 4
    for (int n = 0; n < 64; ++n) {
        const float4 cv = *(const float4*)&CcT[n][t4];   // broadcast
        const float4 bv = *(const float4*)&BcT[n][i4];
        const float ca[4] = {cv.x, cv.y, cv.z, cv.w};
        const float ba[4] = {bv.x, bv.y, bv.z, bv.w};
#pragma unroll
        for (int a = 0; a < 4; ++a)
#pragma unroll
            for (int d = 0; d < 4; ++d) m[a][d] = fmaf(ca[a], ba[d], m[a][d]);
    }
    // decay + causal mask (mask BEFORE exp: avoids inf*0)
    {
        float lat[4], lai[4], dti[4];
#pragma unroll
        for (int a = 0; a < 4; ++a) lat[a] = la_l[t4 + a];
#pragma unroll
        for (int d = 0; d < 4; ++d) { lai[d] = la_l[i4 + d]; dti[d] = dt_l[i4 + d]; }
#pragma unroll
        for (int a = 0; a < 4; ++a)
#pragma unroll
            for (int d = 0; d < 4; ++d) {
                if (i4 + d <= t4 + a)
                    m[a][d] = m[a][d] * dti[d] * __expf(lat[a] - lai[d]);
                else
                    m[a][d] = 0.f;
            }
    }
    __syncthreads();             // BcT consumers done

    // ---- ST[n][p] = S_old[p][n] (transpose write from preloaded regs) ----
    {
        const float sa[16] = {sv0.x, sv0.y, sv0.z, sv0.w, sv1.x, sv1.y, sv1.z, sv1.w,
                              sv2.x, sv2.y, sv2.z, sv2.w, sv3.x, sv3.y, sv3.z, sv3.w};
#pragma unroll
        for (int q = 0; q < 16; ++q) ST[n16 + q][pS] = sa[q];
    }
    __syncthreads();

    // ---- GEMM3: y2[a][b] = sum_n CcT[n][t4+a] * ST[n][p4+b] ----
    float y2[4][4];
#pragma unroll
    for (int a = 0; a < 4; ++a)
#pragma unroll
        for (int d = 0; d < 4; ++d) y2[a][d] = 0.f;
#pragma unroll 4
    for (int n = 0; n < 64; ++n) {
        const float4 cv = *(const float4*)&CcT[n][t4];   // broadcast
        const float4 sv = *(const float4*)&ST[n][i4];
        const float ca[4] = {cv.x, cv.y, cv.z, cv.w};
        const float sa[4] = {sv.x, sv.y, sv.z, sv.w};
#pragma unroll
        for (int a = 0; a < 4; ++a)
#pragma unroll
            for (int d = 0; d < 4; ++d) y2[a][d] = fmaf(ca[a], sa[d], y2[a][d]);
    }
    __syncthreads();             // CcT consumers done

    // ---- MT[i][t] = M[t][i] ----
#pragma unroll
    for (int d = 0; d < 4; ++d)
        *(float4*)&MT[i4 + d][t4] = make_float4(m[0][d], m[1][d], m[2][d], m[3][d]);
    __syncthreads();

    // ---- GEMM2: yac[a][b] = sum_k MT[k][t4+a] * Xs[k][p4+b] ----
    float yac[4][4];
#pragma unroll
    for (int a = 0; a < 4; ++a)
#pragma unroll
        for (int d = 0; d < 4; ++d) yac[a][d] = 0.f;
#pragma unroll 4
    for (int k = 0; k < CHUNK; ++k) {
        const float4 mv = *(const float4*)&MT[k][t4];    // broadcast
        const float4 xv = *(const float4*)&Xs[k][i4];
        const float ma[4] = {mv.x, mv.y, mv.z, mv.w};
        const float xa[4] = {xv.x, xv.y, xv.z, xv.w};
#pragma unroll
        for (int a = 0; a < 4; ++a)
#pragma unroll
            for (int d = 0; d < 4; ++d) yac[a][d] = fmaf(ma[a], xa[d], yac[a][d]);
    }

    // ---- epilogue: Y = yac + a[t]*y2 + D*Xc ; g = Y*silu(z) -> zbuf ----
#pragma unroll
    for (int a = 0; a < 4; ++a) {
        const int t = t4 + a;
        const float at = a_l[t];
        const float4 xv = *(const float4*)&Xs[t][i4];
        const float xa[4] = {xv.x, xv.y, xv.z, xv.w};
        float* zp = zbuf + (row0 + tb + t) * DINNER + h * HEADDIM + i4;
        const float4 zv = *(const float4*)zp;
        const float za[4] = {zv.x, zv.y, zv.z, zv.w};
        float g[4];
#pragma unroll
        for (int d = 0; d < 4; ++d) {
            const float Y = yac[a][d] + at * y2[a][d] + Dh * xa[d];
            g[d] = Y * siluf(za[d]);
        }
        *(float4*)zp = make_float4(g[0], g[1], g[2], g[3]);
    }
}

// ---------------------------------------------------------------------------
// Per-token RMS + value head from g.
// ---------------------------------------------------------------------------
__launch_bounds__(256)
__global__ void rms_val(const float* __restrict__ g, const float* __restrict__ Wv,
                        const float* __restrict__ bval,
                        float* __restrict__ rmsbuf, float* __restrict__ values)
{
    const size_t tok = (size_t)blockIdx.x * 4 + (threadIdx.x >> 6);
    const int lane = threadIdx.x & 63;
    const float4 v = *(const float4*)(g + tok * DINNER + lane * 4);
    const float4 w = *(const float4*)(Wv + lane * 4);
    float ssq = v.x * v.x + v.y * v.y + v.z * v.z + v.w * v.w;
    float gw  = v.x * w.x + v.y * w.y + v.z * w.z + v.w * w.w;
#pragma unroll
    for (int d = 1; d < 64; d <<= 1) {
        ssq += __shfl_xor(ssq, d, 64);
        gw  += __shfl_xor(gw, d, 64);
    }
    if (lane == 0) {
        const float rms = rsqrtf(ssq * (1.f / DINNER) + 1e-5f);
        rmsbuf[tok] = rms;
        values[tok] = gw * rms + bval[0];
    }
}

// ---------------------------------------------------------------------------
extern "C" void kernel_launch(void* const* d_in, const int* in_sizes, int n_in,
                              void* d_out, int out_size, void* d_ws, size_t ws_size,
                              hipStream_t stream)
{
    (void)in_sizes; (void)n_in; (void)out_size; (void)ws_size;
    const float* obs     = (const float*)d_in[0];
    const float* W_enc   = (const float*)d_in[1];
    const float* b_enc   = (const float*)d_in[2];
    const float* W_in    = (const float*)d_in[3];
    const float* W_conv  = (const float*)d_in[4];
    const float* b_conv  = (const float*)d_in[5];
    const float* dt_bias = (const float*)d_in[6];
    const float* A_log   = (const float*)d_in[7];
    const float* Dp      = (const float*)d_in[8];
    const float* norm_w  = (const float*)d_in[9];
    const float* W_out   = (const float*)d_in[10];
    const float* W_act   = (const float*)d_in[11];
    const float* b_act   = (const float*)d_in[12];
    const float* W_val   = (const float*)d_in[13];
    const float* b_val   = (const float*)d_in[14];

    float* logits = (float*)d_out;
    float* values = logits + (size_t)NTOK * NACT;

    char* ws = (char*)d_ws;
    size_t off = 0;
    auto alloc = [&](size_t nfloats) {
        float* ptr = (float*)(ws + off);
        off += ((nfloats * 4 + 255) / 256) * 256;
        return ptr;
    };
    // ws high-water ~ 134.2+134.2+67.1+2.1+134.2+2.1+2.1+~1 = ~477 MB
    float* zbuf   = alloc((size_t)NTOK * DINNER);                    // z -> g in place
    float* xbuf   = alloc((size_t)NTOK * DINNER);
    float* bcbuf  = alloc((size_t)NTOK * BCW2);
    float* dtcol  = alloc((size_t)NTOK * 4);
    float* states = alloc((size_t)NBATCH * NHEADS * NCHUNK * 4096);  // 134.2 MB
    float* hidden = states;   // hidden (67 MB) dead before states written
    float* dtT    = alloc((size_t)NBATCH * NHEADS * TSEQ);
    float* laT    = alloc((size_t)NBATCH * NHEADS * TSEQ);
    float* dApb   = alloc(NBATCH * NHEADS * NCHUNK);
    float* rmsbuf = alloc(NTOK);
    float* Wh     = alloc(DINNER * NACT);
    float* Wv     = alloc(DINNER);

    // 1. fused head weights
    fuse_whead<<<DINNER, NACT, 0, stream>>>(W_out, W_act, W_val, norm_w, Wh, Wv);
    // 2. hidden = obs @ W_enc + b_enc
    gemm_rrr<128, 64, 16><<<dim3(DMODEL / 64, NTOK / 128), 256, 0, stream>>>(
        obs, W_enc, hidden, NTOK, DMODEL, OBSD, OBSD, b_enc, nullptr);
    // 3. segmented in_proj
    gemm_inproj<128, 64, 16><<<dim3((NPROJ + 63) / 64, NTOK / 128), 256, 0, stream>>>(
        hidden, W_in, NTOK, NPROJ, DMODEL, DMODEL, zbuf, xbuf, bcbuf, dtcol);
    // 4. dt / la / dAp
    prep_scan<<<NBATCH * NHEADS * NCHUNK, 64, 0, stream>>>(
        dtcol, dt_bias, A_log, dtT, laT, dApb);
    // 5. phase A: chunk-local states (GEMM form)
    scan_state<<<dim3(NCHUNK, NBATCH * NHEADS), 256, 0, stream>>>(
        xbuf, bcbuf, dtT, laT, W_conv, b_conv, states);
    // 6. phase B0: inter-chunk recurrence
    chunk_scan<<<NBATCH * NHEADS * 16, 256, 0, stream>>>(states, dApb);
    // 7. phase B: outputs (g -> zbuf in place)
    scan_out<<<dim3(NCHUNK, NBATCH * NHEADS), 256, 0, stream>>>(
        xbuf, bcbuf, zbuf, dtT, laT, W_conv, b_conv, Dp, states);
    // 8. per-token rms + value head
    rms_val<<<NTOK / 4, 256, 0, stream>>>(zbuf, Wv, b_val, rmsbuf, values);
    // 9. logits = rms * (g @ Wh) + b_act
    gemm_rrr<128, 64, 16><<<dim3(1, NTOK / 128), 256, 0, stream>>>(
        zbuf, Wh, logits, NTOK, NACT, DINNER, DINNER, b_act, rmsbuf);
}

// Round 10
// 852.595 us; speedup vs baseline: 1.3791x; 1.1924x over previous
//
#include <hip/hip_runtime.h>
#include <math.h>

#define OBSD   256
#define TSEQ   4096
#define NBATCH 32
#define DMODEL 128
#define DSTATE 64
#define DINNER 256
#define NHEADS 4
#define HEADDIM 64
#define NPROJ  644
#define NPPAD  704   // in_proj N padded to 11*64
#define NTOK   (NBATCH*TSEQ)
#define CHUNK  64
#define NCHUNK (TSEQ/CHUNK)
#define NACT   64
#define BCW2   128   // bcbuf row width (B 64 | C 64)
#define LP     68    // padded LDS row stride (scan kernels)

typedef __attribute__((ext_vector_type(8))) short bf16x8;
typedef __attribute__((ext_vector_type(4))) float f32x4;
typedef __attribute__((ext_vector_type(8))) unsigned short u16x8;
typedef __attribute__((ext_vector_type(4))) unsigned short u16x4;

__device__ __forceinline__ float siluf(float x) { return x / (1.f + __expf(-x)); }

// round-to-nearest-even bf16 (bit pattern) and hi/lo split: v ~= hi + lo
__device__ __forceinline__ unsigned short bfhi(float v) {
    unsigned u = __float_as_uint(v);
    return (unsigned short)((u + 0x7FFFu + ((u >> 16) & 1u)) >> 16);
}
__device__ __forceinline__ void splitbf(float v, unsigned short& hi, unsigned short& lo) {
    hi = bfhi(v);
    const float hf = __uint_as_float((unsigned)hi << 16);
    lo = bfhi(v - hf);
}

// ---------------------------------------------------------------------------
// Split-bf16 MFMA GEMM:  C = A @ B^T_layout  (A: [M][K] bf16 hi/lo row-major,
// BT: [Npad][K] bf16 hi/lo = B transposed).  3 passes: hi*hi + hi*lo + lo*hi
// gives ~fp32 accuracy (rel err ~2^-16) with fp32 MFMA accumulation.
// BM=128 (4 waves x 32 rows), BN=64, BK=32. LDS 30 KB -> 5 blocks/CU.
// Fragment layout per guide m97/m89 (verified): A row=lane&15, k=(lane>>4)*8+j;
// B(T) col=lane&15, same k; D col=lane&15, row=(lane>>4)*4+reg.
// SEG=0: C[M][NACT] + bias.  SEG=1: segmented in_proj epilogue + bias.
// ---------------------------------------------------------------------------
template<int SEG>
__launch_bounds__(256)
__global__ void mfma_gemm(const unsigned short* __restrict__ Ahi,
                          const unsigned short* __restrict__ Alo,
                          const unsigned short* __restrict__ BThi,
                          const unsigned short* __restrict__ BTlo,
                          int K, const float* __restrict__ bias,
                          float* __restrict__ C,
                          float* __restrict__ zbuf, float* __restrict__ xbuf,
                          float* __restrict__ bcbuf, float* __restrict__ dtcol)
{
    __shared__ unsigned short Ah[128][40], Al[128][40];   // 32 k + 8 pad
    __shared__ unsigned short Bh[64][40],  Bl[64][40];    // total 30 KB
    const int tid  = threadIdx.x;
    const int wave = tid >> 6, lane = tid & 63;
    const int l15 = lane & 15, l4 = lane >> 4;
    const int m0 = blockIdx.y * 128, n0 = blockIdx.x * 64;

    f32x4 acc[2][4];
#pragma unroll
    for (int rt = 0; rt < 2; ++rt)
#pragma unroll
        for (int ct = 0; ct < 4; ++ct) acc[rt][ct] = (f32x4){0.f, 0.f, 0.f, 0.f};

    const int ar  = tid >> 1;           // A row 0..127
    const int akc = (tid & 1) * 16;     // k chunk base (this thread: akc, akc+8)
    const int br  = tid >> 2;           // B row (n) 0..63
    const int bkc = (tid & 3) * 8;

    for (int k0 = 0; k0 < K; k0 += 32) {
        {
            const size_t ab = (size_t)(m0 + ar) * K + k0 + akc;
            *(u16x8*)&Ah[ar][akc]     = *(const u16x8*)(Ahi + ab);
            *(u16x8*)&Ah[ar][akc + 8] = *(const u16x8*)(Ahi + ab + 8);
            *(u16x8*)&Al[ar][akc]     = *(const u16x8*)(Alo + ab);
            *(u16x8*)&Al[ar][akc + 8] = *(const u16x8*)(Alo + ab + 8);
            const size_t bb = (size_t)(n0 + br) * K + k0 + bkc;
            *(u16x8*)&Bh[br][bkc] = *(const u16x8*)(BThi + bb);
            *(u16x8*)&Bl[br][bkc] = *(const u16x8*)(BTlo + bb);
        }
        __syncthreads();

        const int kk = l4 * 8;
        bf16x8 ah[2], al[2], bh[4], bl[4];
#pragma unroll
        for (int rt = 0; rt < 2; ++rt) {
            const int r = wave * 32 + rt * 16 + l15;
            ah[rt] = *(const bf16x8*)&Ah[r][kk];
            al[rt] = *(const bf16x8*)&Al[r][kk];
        }
#pragma unroll
        for (int ct = 0; ct < 4; ++ct) {
            const int n = ct * 16 + l15;
            bh[ct] = *(const bf16x8*)&Bh[n][kk];
            bl[ct] = *(const bf16x8*)&Bl[n][kk];
        }
#pragma unroll
        for (int rt = 0; rt < 2; ++rt)
#pragma unroll
            for (int ct = 0; ct < 4; ++ct) {
                acc[rt][ct] = __builtin_amdgcn_mfma_f32_16x16x32_bf16(ah[rt], bh[ct], acc[rt][ct], 0, 0, 0);
                acc[rt][ct] = __builtin_amdgcn_mfma_f32_16x16x32_bf16(ah[rt], bl[ct], acc[rt][ct], 0, 0, 0);
                acc[rt][ct] = __builtin_amdgcn_mfma_f32_16x16x32_bf16(al[rt], bh[ct], acc[rt][ct], 0, 0, 0);
            }
        __syncthreads();
    }

#pragma unroll
    for (int rt = 0; rt < 2; ++rt) {
        const int rbase = m0 + wave * 32 + rt * 16 + l4 * 4;
#pragma unroll
        for (int ct = 0; ct < 4; ++ct) {
            const int cg = n0 + ct * 16 + l15;
            const float bv = bias[cg];
#pragma unroll
            for (int j = 0; j < 4; ++j) {
                const float v = acc[rt][ct][j] + bv;
                const size_t r = (size_t)(rbase + j);
                if constexpr (SEG == 0) {
                    C[r * NACT + cg] = v;
                } else {
                    if (cg < 256)      zbuf[r * DINNER + cg] = v;
                    else if (cg < 512) xbuf[r * DINNER + (cg - 256)] = v;
                    else if (cg < 640) bcbuf[r * BCW2 + (cg - 512)] = v;
                    else if (cg < NPROJ) dtcol[r * 4 + (cg - 640)] = v;
                }
            }
        }
    }
}

// ---------------------------------------------------------------------------
// Wc = W_enc @ W_in (fp32), emitted TRANSPOSED + split bf16: WcT[n][r], and
// bz[n] = b_enc @ W_in column n. n >= NPROJ rows are zero padding.
// ---------------------------------------------------------------------------
__global__ void make_wc(const float* __restrict__ W_enc, const float* __restrict__ W_in,
                        const float* __restrict__ b_enc,
                        unsigned short* __restrict__ WcThi, unsigned short* __restrict__ WcTlo,
                        float* __restrict__ bz)
{
    const int n = blockIdx.x;      // 0..NPPAD-1
    const int r = threadIdx.x;     // 0..255
    float v = 0.f;
    if (n < NPROJ)
        for (int k = 0; k < DMODEL; ++k)
            v = fmaf(W_enc[r * DMODEL + k], W_in[k * NPROJ + n], v);
    unsigned short hi, lo; splitbf(v, hi, lo);
    WcThi[n * OBSD + r] = hi;
    WcTlo[n * OBSD + r] = lo;
    if (r == 0) {
        float bv = 0.f;
        if (n < NPROJ)
            for (int k = 0; k < DMODEL; ++k)
                bv = fmaf(b_enc[k], W_in[k * NPROJ + n], bv);
        bz[n] = bv;
    }
}

// ---------------------------------------------------------------------------
// Fused head weights, emitted transposed+split: WhT[j][k]; Wv fp32.
// ---------------------------------------------------------------------------
__global__ void fuse_whead(const float* __restrict__ W_out, const float* __restrict__ W_act,
                           const float* __restrict__ W_val, const float* __restrict__ norm_w,
                           unsigned short* __restrict__ WhThi, unsigned short* __restrict__ WhTlo,
                           float* __restrict__ Wv)
{
    const int k = blockIdx.x;      // 0..255
    const int j = threadIdx.x;     // 0..63
    float s = 0.f;
    for (int m = 0; m < DMODEL; ++m)
        s = fmaf(W_out[k * DMODEL + m], W_act[m * NACT + j], s);
    s *= norm_w[k];
    unsigned short hi, lo; splitbf(s, hi, lo);
    WhThi[j * DINNER + k] = hi;
    WhTlo[j * DINNER + k] = lo;
    if (j == 0) {
        float sv = 0.f;
        for (int m = 0; m < DMODEL; ++m)
            sv = fmaf(W_out[k * DMODEL + m], W_val[m], sv);
        Wv[k] = sv * norm_w[k];
    }
}

// ---------------------------------------------------------------------------
// obs fp32 -> bf16 hi/lo buffers (grid-stride, float4 granularity).
// ---------------------------------------------------------------------------
__global__ void conv_obs(const float* __restrict__ obs,
                         unsigned short* __restrict__ Ahi, unsigned short* __restrict__ Alo)
{
    const size_t total = (size_t)NTOK * OBSD / 4;
    for (size_t i = (size_t)blockIdx.x * blockDim.x + threadIdx.x; i < total;
         i += (size_t)gridDim.x * blockDim.x) {
        const float4 v = ((const float4*)obs)[i];
        u16x4 h, l;
        splitbf(v.x, ((unsigned short*)&h)[0], ((unsigned short*)&l)[0]);
        splitbf(v.y, ((unsigned short*)&h)[1], ((unsigned short*)&l)[1]);
        splitbf(v.z, ((unsigned short*)&h)[2], ((unsigned short*)&l)[2]);
        splitbf(v.w, ((unsigned short*)&h)[3], ((unsigned short*)&l)[3]);
        ((u16x4*)Ahi)[i] = h;
        ((u16x4*)Alo)[i] = l;
    }
}

// ---------------------------------------------------------------------------
// prep: per (bh, chunk): dt = softplus, la = inclusive cumsum(dt*A) within
// chunk (wave scan), dAp = exp(la[63]).
// ---------------------------------------------------------------------------
__global__ void prep_scan(const float* __restrict__ dtcol, const float* __restrict__ dt_bias,
                          const float* __restrict__ A_log,
                          float* __restrict__ dtT, float* __restrict__ laT,
                          float* __restrict__ dApbuf)
{
    const int bc = blockIdx.x;
    const int bh = bc >> 6, c = bc & 63;
    const int b = bh >> 2, h = bh & 3;
    const int lane = threadIdx.x;
    const size_t tok = (size_t)b * TSEQ + c * CHUNK + lane;
    const float x = dtcol[tok * 4 + h] + dt_bias[h];
    const float dt = (x > 20.f) ? x : log1pf(expf(x));
    const float A = -expf(A_log[h]);
    float v = dt * A;
#pragma unroll
    for (int d = 1; d < 64; d <<= 1) {
        const float o = __shfl_up(v, d, 64);
        if (lane >= d) v += o;
    }
    const size_t o = (size_t)bh * TSEQ + c * CHUNK + lane;
    dtT[o] = dt;
    laT[o] = v;
    if (lane == 63) dApbuf[bh * NCHUNK + c] = __expf(v);
}

// ---------------------------------------------------------------------------
// Phase A: chunk-local states via GEMM (unchanged from round 9).
// ---------------------------------------------------------------------------
__launch_bounds__(256)
__global__ void scan_state(const float* __restrict__ xbuf, const float* __restrict__ bcbuf,
                           const float* __restrict__ dtT, const float* __restrict__ laT,
                           const float* __restrict__ W_conv, const float* __restrict__ b_conv,
                           float* __restrict__ states)
{
    __shared__ float Xs[CHUNK][LP];
    __shared__ float Bw[CHUNK][LP];
    __shared__ float w_l[CHUNK];
    const int c = blockIdx.x, bh = blockIdx.y;
    const int b = bh >> 2, h = bh & 3;
    const int tid = threadIdx.x;
    const size_t row0 = (size_t)b * TSEQ;
    const int tb = c * CHUNK;

    if (tid < CHUNK) {
        const size_t o = (size_t)bh * TSEQ + tb;
        const float laLast = laT[o + CHUNK - 1];
        w_l[tid] = dtT[o + tid] * __expf(laLast - laT[o + tid]);
    }
    __syncthreads();

    const int sg = tid & 15, st = tid >> 4;
    const int t4 = st * 4;

    {
        const int ch = h * HEADDIM + sg * 4;
        float w[4][4], bb[4];
#pragma unroll
        for (int j = 0; j < 4; ++j) {
            bb[j] = b_conv[ch + j];
#pragma unroll
            for (int k = 0; k < 4; ++k) w[j][k] = W_conv[(ch + j) * 4 + k];
        }
        float rx[4][7];
#pragma unroll
        for (int r = 0; r < 7; ++r) {
            const int tg = tb + t4 - 3 + r;
            float4 v = make_float4(0.f, 0.f, 0.f, 0.f);
            if (tg >= 0) v = *(const float4*)(xbuf + (row0 + tg) * DINNER + ch);
            rx[0][r] = v.x; rx[1][r] = v.y; rx[2][r] = v.z; rx[3][r] = v.w;
        }
#pragma unroll
        for (int i = 0; i < 4; ++i) {
            float o[4];
#pragma unroll
            for (int j = 0; j < 4; ++j)
                o[j] = siluf(fmaf(rx[j][i + 3], w[j][3], fmaf(rx[j][i + 2], w[j][2],
                             fmaf(rx[j][i + 1], w[j][1], fmaf(rx[j][i], w[j][0], bb[j])))));
            *(float4*)&Xs[t4 + i][sg * 4] = make_float4(o[0], o[1], o[2], o[3]);
        }
    }
    {
        const int ch = sg * 4;
        float w[4][4], bb[4];
#pragma unroll
        for (int j = 0; j < 4; ++j) {
            bb[j] = b_conv[DINNER + ch + j];
#pragma unroll
            for (int k = 0; k < 4; ++k) w[j][k] = W_conv[(DINNER + ch + j) * 4 + k];
        }
        float rx[4][7];
#pragma unroll
        for (int r = 0; r < 7; ++r) {
            const int tg = tb + t4 - 3 + r;
            float4 v = make_float4(0.f, 0.f, 0.f, 0.f);
            if (tg >= 0) v = *(const float4*)(bcbuf + (row0 + tg) * BCW2 + ch);
            rx[0][r] = v.x; rx[1][r] = v.y; rx[2][r] = v.z; rx[3][r] = v.w;
        }
#pragma unroll
        for (int i = 0; i < 4; ++i) {
            const float wi = w_l[t4 + i];
            float o[4];
#pragma unroll
            for (int j = 0; j < 4; ++j)
                o[j] = wi * siluf(fmaf(rx[j][i + 3], w[j][3], fmaf(rx[j][i + 2], w[j][2],
                              fmaf(rx[j][i + 1], w[j][1], fmaf(rx[j][i], w[j][0], bb[j])))));
            *(float4*)&Bw[t4 + i][sg * 4] = make_float4(o[0], o[1], o[2], o[3]);
        }
    }
    __syncthreads();

    const int pn = tid & 15, pp = tid >> 4;
    const int n4 = pn * 4, p4 = pp * 4;
    float acc[4][4];
#pragma unroll
    for (int a = 0; a < 4; ++a)
#pragma unroll
        for (int d = 0; d < 4; ++d) acc[a][d] = 0.f;
#pragma unroll 4
    for (int i = 0; i < CHUNK; ++i) {
        const float4 xv = *(const float4*)&Xs[i][p4];
        const float4 bv = *(const float4*)&Bw[i][n4];
        const float xa[4] = {xv.x, xv.y, xv.z, xv.w};
        const float ba[4] = {bv.x, bv.y, bv.z, bv.w};
#pragma unroll
        for (int a = 0; a < 4; ++a)
#pragma unroll
            for (int d = 0; d < 4; ++d) acc[a][d] = fmaf(xa[a], ba[d], acc[a][d]);
    }
    const size_t so = (size_t)(bh * NCHUNK + c) * 4096;
#pragma unroll
    for (int a = 0; a < 4; ++a)
        *(float4*)(states + so + (size_t)(p4 + a) * 64 + n4) =
            make_float4(acc[a][0], acc[a][1], acc[a][2], acc[a][3]);
}

// ---------------------------------------------------------------------------
__global__ void chunk_scan(float* __restrict__ states, const float* __restrict__ dAprod)
{
    __shared__ float sdA[NCHUNK];
    const int bh = blockIdx.x >> 4;
    const int elem = ((blockIdx.x & 15) << 8) | threadIdx.x;
    if (threadIdx.x < NCHUNK) sdA[threadIdx.x] = dAprod[bh * NCHUNK + threadIdx.x];
    __syncthreads();
    const size_t base = (size_t)bh * NCHUNK * 4096 + elem;
    float s0 = 0.f;
    for (int c = 0; c < NCHUNK; ++c) {
        const size_t off = base + (size_t)c * 4096;
        const float Sc = states[off];
        states[off] = s0;
        s0 = fmaf(sdA[c], s0, Sc);
    }
}

// ---------------------------------------------------------------------------
// Phase B: outputs via 3 micro-GEMMs per (bh, chunk) (unchanged from round 9).
// ---------------------------------------------------------------------------
__launch_bounds__(256)
__global__ void scan_out(const float* __restrict__ xbuf, const float* __restrict__ bcbuf,
                         float* zbuf,
                         const float* __restrict__ dtT, const float* __restrict__ laT,
                         const float* __restrict__ W_conv, const float* __restrict__ b_conv,
                         const float* __restrict__ Dparam,
                         const float* __restrict__ states)
{
    __shared__ float BcT[CHUNK][LP];
    __shared__ float CcT[CHUNK][LP];
    __shared__ float Xs[CHUNK][LP];
    __shared__ float la_l[CHUNK], dt_l[CHUNK], a_l[CHUNK];
    float (*ST)[LP] = BcT;
    float (*MT)[LP] = CcT;

    const int c = blockIdx.x, bh = blockIdx.y;
    const int b = bh >> 2, h = bh & 3;
    const int tid = threadIdx.x;
    const size_t row0 = (size_t)b * TSEQ;
    const int tb = c * CHUNK;
    const float Dh = Dparam[h];

    const int pS = tid >> 2;
    const int n16 = (tid & 3) * 16;
    const float* Sg = states + (size_t)(bh * NCHUNK + c) * 4096 + (size_t)pS * 64 + n16;
    const float4 sv0 = *(const float4*)(Sg + 0);
    const float4 sv1 = *(const float4*)(Sg + 4);
    const float4 sv2 = *(const float4*)(Sg + 8);
    const float4 sv3 = *(const float4*)(Sg + 12);

    if (tid < CHUNK) {
        const size_t o = (size_t)bh * TSEQ + tb + tid;
        const float la = laT[o];
        la_l[tid] = la;
        dt_l[tid] = dtT[o];
        a_l[tid] = __expf(la);
    }

    const int sg = tid & 15, st = tid >> 4;
    const int t4s = st * 4;

    {
        const int ch = h * HEADDIM + sg * 4;
        float w[4][4], bb[4];
#pragma unroll
        for (int j = 0; j < 4; ++j) {
            bb[j] = b_conv[ch + j];
#pragma unroll
            for (int k = 0; k < 4; ++k) w[j][k] = W_conv[(ch + j) * 4 + k];
        }
        float rx[4][7];
#pragma unroll
        for (int r = 0; r < 7; ++r) {
            const int tg = tb + t4s - 3 + r;
            float4 v = make_float4(0.f, 0.f, 0.f, 0.f);
            if (tg >= 0) v = *(const float4*)(xbuf + (row0 + tg) * DINNER + ch);
            rx[0][r] = v.x; rx[1][r] = v.y; rx[2][r] = v.z; rx[3][r] = v.w;
        }
#pragma unroll
        for (int i = 0; i < 4; ++i) {
            float o[4];
#pragma unroll
            for (int j = 0; j < 4; ++j)
                o[j] = siluf(fmaf(rx[j][i + 3], w[j][3], fmaf(rx[j][i + 2], w[j][2],
                             fmaf(rx[j][i + 1], w[j][1], fmaf(rx[j][i], w[j][0], bb[j])))));
            *(float4*)&Xs[t4s + i][sg * 4] = make_float4(o[0], o[1], o[2], o[3]);
        }
    }
    {
        const int ch = sg * 4;
        float w[4][4], bb[4];
#pragma unroll
        for (int j = 0; j < 4; ++j) {
            bb[j] = b_conv[DINNER + ch + j];
#pragma unroll
            for (int k = 0; k < 4; ++k) w[j][k] = W_conv[(DINNER + ch + j) * 4 + k];
        }
        float rx[4][7];
#pragma unroll
        for (int r = 0; r < 7; ++r) {
            const int tg = tb + t4s - 3 + r;
            float4 v = make_float4(0.f, 0.f, 0.f, 0.f);
            if (tg >= 0) v = *(const float4*)(bcbuf + (row0 + tg) * BCW2 + ch);
            rx[0][r] = v.x; rx[1][r] = v.y; rx[2][r] = v.z; rx[3][r] = v.w;
        }
#pragma unroll
        for (int j = 0; j < 4; ++j) {
            float o[4];
#pragma unroll
            for (int i = 0; i < 4; ++i)
                o[i] = siluf(fmaf(rx[j][i + 3], w[j][3], fmaf(rx[j][i + 2], w[j][2],
                             fmaf(rx[j][i + 1], w[j][1], fmaf(rx[j][i], w[j][0], bb[j])))));
            *(float4*)&BcT[ch + j][t4s] = make_float4(o[0], o[1], o[2], o[3]);
        }
    }
    {
        const int ch = sg * 4;
        float w[4][4], bb[4];
#pragma unroll
        for (int j = 0; j < 4; ++j) {
            bb[j] = b_conv[DINNER + 64 + ch + j];
#pragma unroll
            for (int k = 0; k < 4; ++k) w[j][k] = W_conv[(DINNER + 64 + ch + j) * 4 + k];
        }
        float rx[4][7];
#pragma unroll
        for (int r = 0; r < 7; ++r) {
            const int tg = tb + t4s - 3 + r;
            float4 v = make_float4(0.f, 0.f, 0.f, 0.f);
            if (tg >= 0) v = *(const float4*)(bcbuf + (row0 + tg) * BCW2 + 64 + ch);
            rx[0][r] = v.x; rx[1][r] = v.y; rx[2][r] = v.z; rx[3][r] = v.w;
        }
#pragma unroll
        for (int j = 0; j < 4; ++j) {
            float o[4];
#pragma unroll
            for (int i = 0; i < 4; ++i)
                o[i] = siluf(fmaf(rx[j][i + 3], w[j][3], fmaf(rx[j][i + 2], w[j][2],
                             fmaf(rx[j][i + 1], w[j][1], fmaf(rx[j][i], w[j][0], bb[j])))));
            *(float4*)&CcT[ch + j][t4s] = make_float4(o[0], o[1], o[2], o[3]);
        }
    }
    __syncthreads();

    const int ti = tid & 15, tt = tid >> 4;
    const int i4 = ti * 4, t4 = tt * 4;

    float m[4][4];
#pragma unroll
    for (int a = 0; a < 4; ++a)
#pragma unroll
        for (int d = 0; d < 4; ++d) m[a][d] = 0.f;
#pragma unroll 4
    for (int n = 0; n < 64; ++n) {
        const float4 cv = *(const float4*)&CcT[n][t4];
        const float4 bv = *(const float4*)&BcT[n][i4];
        const float ca[4] = {cv.x, cv.y, cv.z, cv.w};
        const float ba[4] = {bv.x, bv.y, bv.z, bv.w};
#pragma unroll
        for (int a = 0; a < 4; ++a)
#pragma unroll
            for (int d = 0; d < 4; ++d) m[a][d] = fmaf(ca[a], ba[d], m[a][d]);
    }
    {
        float lat[4], lai[4], dti[4];
#pragma unroll
        for (int a = 0; a < 4; ++a) lat[a] = la_l[t4 + a];
#pragma unroll
        for (int d = 0; d < 4; ++d) { lai[d] = la_l[i4 + d]; dti[d] = dt_l[i4 + d]; }
#pragma unroll
        for (int a = 0; a < 4; ++a)
#pragma unroll
            for (int d = 0; d < 4; ++d) {
                if (i4 + d <= t4 + a)
                    m[a][d] = m[a][d] * dti[d] * __expf(lat[a] - lai[d]);
                else
                    m[a][d] = 0.f;
            }
    }
    __syncthreads();

    {
        const float sa[16] = {sv0.x, sv0.y, sv0.z, sv0.w, sv1.x, sv1.y, sv1.z, sv1.w,
                              sv2.x, sv2.y, sv2.z, sv2.w, sv3.x, sv3.y, sv3.z, sv3.w};
#pragma unroll
        for (int q = 0; q < 16; ++q) ST[n16 + q][pS] = sa[q];
    }
    __syncthreads();

    float y2[4][4];
#pragma unroll
    for (int a = 0; a < 4; ++a)
#pragma unroll
        for (int d = 0; d < 4; ++d) y2[a][d] = 0.f;
#pragma unroll 4
    for (int n = 0; n < 64; ++n) {
        const float4 cv = *(const float4*)&CcT[n][t4];
        const float4 sv = *(const float4*)&ST[n][i4];
        const float ca[4] = {cv.x, cv.y, cv.z, cv.w};
        const float sa[4] = {sv.x, sv.y, sv.z, sv.w};
#pragma unroll
        for (int a = 0; a < 4; ++a)
#pragma unroll
            for (int d = 0; d < 4; ++d) y2[a][d] = fmaf(ca[a], sa[d], y2[a][d]);
    }
    __syncthreads();

#pragma unroll
    for (int d = 0; d < 4; ++d)
        *(float4*)&MT[i4 + d][t4] = make_float4(m[0][d], m[1][d], m[2][d], m[3][d]);
    __syncthreads();

    float yac[4][4];
#pragma unroll
    for (int a = 0; a < 4; ++a)
#pragma unroll
        for (int d = 0; d < 4; ++d) yac[a][d] = 0.f;
#pragma unroll 4
    for (int k = 0; k < CHUNK; ++k) {
        const float4 mv = *(const float4*)&MT[k][t4];
        const float4 xv = *(const float4*)&Xs[k][i4];
        const float ma[4] = {mv.x, mv.y, mv.z, mv.w};
        const float xa[4] = {xv.x, xv.y, xv.z, xv.w};
#pragma unroll
        for (int a = 0; a < 4; ++a)
#pragma unroll
            for (int d = 0; d < 4; ++d) yac[a][d] = fmaf(ma[a], xa[d], yac[a][d]);
    }

#pragma unroll
    for (int a = 0; a < 4; ++a) {
        const int t = t4 + a;
        const float at = a_l[t];
        const float4 xv = *(const float4*)&Xs[t][i4];
        const float xa[4] = {xv.x, xv.y, xv.z, xv.w};
        float* zp = zbuf + (row0 + tb + t) * DINNER + h * HEADDIM + i4;
        const float4 zv = *(const float4*)zp;
        const float za[4] = {zv.x, zv.y, zv.z, zv.w};
        float g[4];
#pragma unroll
        for (int d = 0; d < 4; ++d) {
            const float Y = yac[a][d] + at * y2[a][d] + Dh * xa[d];
            g[d] = Y * siluf(za[d]);
        }
        *(float4*)zp = make_float4(g[0], g[1], g[2], g[3]);
    }
}

// ---------------------------------------------------------------------------
// Per-token RMS + value head; also emits rms-scaled g as bf16 hi/lo for the
// MFMA logits GEMM (rowscale absorbed into Ghi/Glo).
// ---------------------------------------------------------------------------
__launch_bounds__(256)
__global__ void rms_val(const float* __restrict__ g, const float* __restrict__ Wv,
                        const float* __restrict__ bval, float* __restrict__ values,
                        unsigned short* __restrict__ Ghi, unsigned short* __restrict__ Glo)
{
    const size_t tok = (size_t)blockIdx.x * 4 + (threadIdx.x >> 6);
    const int lane = threadIdx.x & 63;
    const float4 v = *(const float4*)(g + tok * DINNER + lane * 4);
    const float4 w = *(const float4*)(Wv + lane * 4);
    float ssq = v.x * v.x + v.y * v.y + v.z * v.z + v.w * v.w;
    float gw  = v.x * w.x + v.y * w.y + v.z * w.z + v.w * w.w;
#pragma unroll
    for (int d = 1; d < 64; d <<= 1) {
        ssq += __shfl_xor(ssq, d, 64);
        gw  += __shfl_xor(gw, d, 64);
    }
    const float rms = rsqrtf(ssq * (1.f / DINNER) + 1e-5f);
    u16x4 h, l;
    splitbf(v.x * rms, ((unsigned short*)&h)[0], ((unsigned short*)&l)[0]);
    splitbf(v.y * rms, ((unsigned short*)&h)[1], ((unsigned short*)&l)[1]);
    splitbf(v.z * rms, ((unsigned short*)&h)[2], ((unsigned short*)&l)[2]);
    splitbf(v.w * rms, ((unsigned short*)&h)[3], ((unsigned short*)&l)[3]);
    *(u16x4*)(Ghi + tok * DINNER + lane * 4) = h;
    *(u16x4*)(Glo + tok * DINNER + lane * 4) = l;
    if (lane == 0) values[tok] = gw * rms + bval[0];
}

// ---------------------------------------------------------------------------
extern "C" void kernel_launch(void* const* d_in, const int* in_sizes, int n_in,
                              void* d_out, int out_size, void* d_ws, size_t ws_size,
                              hipStream_t stream)
{
    (void)in_sizes; (void)n_in; (void)out_size; (void)ws_size;
    const float* obs     = (const float*)d_in[0];
    const float* W_enc   = (const float*)d_in[1];
    const float* b_enc   = (const float*)d_in[2];
    const float* W_in    = (const float*)d_in[3];
    const float* W_conv  = (const float*)d_in[4];
    const float* b_conv  = (const float*)d_in[5];
    const float* dt_bias = (const float*)d_in[6];
    const float* A_log   = (const float*)d_in[7];
    const float* Dp      = (const float*)d_in[8];
    const float* norm_w  = (const float*)d_in[9];
    const float* W_out   = (const float*)d_in[10];
    const float* W_act   = (const float*)d_in[11];
    const float* b_act   = (const float*)d_in[12];
    const float* W_val   = (const float*)d_in[13];
    const float* b_val   = (const float*)d_in[14];

    float* logits = (float*)d_out;
    float* values = logits + (size_t)NTOK * NACT;

    char* ws = (char*)d_ws;
    size_t off = 0;
    auto alloc = [&](size_t nbytes) {
        char* ptr = ws + off;
        off += (nbytes + 255) / 256 * 256;
        return ptr;
    };
    // high-water ~ 134.2*2 + 67.1 + 2.1 + 134.2(shared) + small = ~477 MB
    float* zbuf   = (float*)alloc((size_t)NTOK * DINNER * 4);   // z -> g in place
    float* xbuf   = (float*)alloc((size_t)NTOK * DINNER * 4);
    float* bcbuf  = (float*)alloc((size_t)NTOK * BCW2 * 4);
    float* dtcol  = (float*)alloc((size_t)NTOK * 4 * 4);
    // shared 134.2 MB region: obs-bf16 (steps 3-4) -> states (5-8) -> g-bf16 (9-10)
    char*  shared = alloc((size_t)NTOK * OBSD * 2 * 2);
    unsigned short* Ahi = (unsigned short*)shared;
    unsigned short* Alo = Ahi + (size_t)NTOK * OBSD;
    float* states = (float*)shared;                             // 128*64*4096*4 = same size
    unsigned short* Ghi = (unsigned short*)shared;
    unsigned short* Glo = Ghi + (size_t)NTOK * DINNER;
    float* dtT    = (float*)alloc((size_t)NBATCH * NHEADS * TSEQ * 4);
    float* laT    = (float*)alloc((size_t)NBATCH * NHEADS * TSEQ * 4);
    float* dApb   = (float*)alloc(NBATCH * NHEADS * NCHUNK * 4);
    unsigned short* WcThi = (unsigned short*)alloc((size_t)NPPAD * OBSD * 2);
    unsigned short* WcTlo = (unsigned short*)alloc((size_t)NPPAD * OBSD * 2);
    float* bz     = (float*)alloc(NPPAD * 4);
    unsigned short* WhThi = (unsigned short*)alloc((size_t)NACT * DINNER * 2);
    unsigned short* WhTlo = (unsigned short*)alloc((size_t)NACT * DINNER * 2);
    float* Wv     = (float*)alloc(DINNER * 4);

    // 1. fused head weights (transposed + split bf16)
    fuse_whead<<<DINNER, NACT, 0, stream>>>(W_out, W_act, W_val, norm_w, WhThi, WhTlo, Wv);
    // 2. Wc = W_enc @ W_in (transposed + split bf16) + bz
    make_wc<<<NPPAD, 256, 0, stream>>>(W_enc, W_in, b_enc, WcThi, WcTlo, bz);
    // 3. obs -> bf16 hi/lo
    conv_obs<<<2048, 256, 0, stream>>>(obs, Ahi, Alo);
    // 4. in_proj via split-bf16 MFMA: zxbcdt = obs @ Wc + bz (segmented epilogue)
    mfma_gemm<1><<<dim3(NPPAD / 64, NTOK / 128), 256, 0, stream>>>(
        Ahi, Alo, WcThi, WcTlo, OBSD, bz, nullptr, zbuf, xbuf, bcbuf, dtcol);
    // 5. dt / la / dAp
    prep_scan<<<NBATCH * NHEADS * NCHUNK, 64, 0, stream>>>(
        dtcol, dt_bias, A_log, dtT, laT, dApb);
    // 6. phase A: chunk-local states
    scan_state<<<dim3(NCHUNK, NBATCH * NHEADS), 256, 0, stream>>>(
        xbuf, bcbuf, dtT, laT, W_conv, b_conv, states);
    // 7. inter-chunk recurrence
    chunk_scan<<<NBATCH * NHEADS * 16, 256, 0, stream>>>(states, dApb);
    // 8. phase B: outputs (g -> zbuf in place)
    scan_out<<<dim3(NCHUNK, NBATCH * NHEADS), 256, 0, stream>>>(
        xbuf, bcbuf, zbuf, dtT, laT, W_conv, b_conv, Dp, states);
    // 9. rms + value head + g*rms -> bf16 hi/lo
    rms_val<<<NTOK / 4, 256, 0, stream>>>(zbuf, Wv, b_val, values, Ghi, Glo);
    // 10. logits = (g*rms) @ Wh + b_act via split-bf16 MFMA
    mfma_gemm<0><<<dim3(1, NTOK / 128), 256, 0, stream>>>(
        Ghi, Glo, WhThi, WhTlo, DINNER, b_act, logits, nullptr, nullptr, nullptr, nullptr);
}

// Round 17
// 849.337 us; speedup vs baseline: 1.3844x; 1.0038x over previous
//
#include <hip/hip_runtime.h>
#include <math.h>

#define OBSD   256
#define TSEQ   4096
#define NBATCH 32
#define DMODEL 128
#define DSTATE 64
#define DINNER 256
#define NHEADS 4
#define HEADDIM 64
#define NPROJ  644
#define NPPAD  704   // in_proj N padded to 11*64
#define NTOK   (NBATCH*TSEQ)
#define CHUNK  64
#define NCHUNK (TSEQ/CHUNK)
#define NACT   64
#define BCW2   128   // bcbuf row width (B 64 | C 64)
#define LP     68    // padded LDS row stride (scan kernels)

typedef __attribute__((ext_vector_type(8))) short bf16x8;
typedef __attribute__((ext_vector_type(4))) float f32x4;
typedef __attribute__((ext_vector_type(8))) unsigned short u16x8;
typedef __attribute__((ext_vector_type(4))) unsigned short u16x4;

__device__ __forceinline__ float siluf(float x) { return x / (1.f + __expf(-x)); }

// round-to-nearest-even bf16 (bit pattern) and hi/lo split: v ~= hi + lo
__device__ __forceinline__ unsigned short bfhi(float v) {
    unsigned u = __float_as_uint(v);
    return (unsigned short)((u + 0x7FFFu + ((u >> 16) & 1u)) >> 16);
}
__device__ __forceinline__ void splitbf(float v, unsigned short& hi, unsigned short& lo) {
    hi = bfhi(v);
    const float hf = __uint_as_float((unsigned)hi << 16);
    lo = bfhi(v - hf);
}

// ---------------------------------------------------------------------------
// Split-bf16 MFMA GEMM (HW-verified round 10).
// ---------------------------------------------------------------------------
template<int SEG>
__launch_bounds__(256)
__global__ void mfma_gemm(const unsigned short* __restrict__ Ahi,
                          const unsigned short* __restrict__ Alo,
                          const unsigned short* __restrict__ BThi,
                          const unsigned short* __restrict__ BTlo,
                          int K, const float* __restrict__ bias,
                          float* __restrict__ C,
                          float* __restrict__ zbuf, float* __restrict__ xbuf,
                          float* __restrict__ bcbuf, float* __restrict__ dtcol)
{
    __shared__ __align__(16) unsigned short Ah[128][40], Al[128][40];
    __shared__ __align__(16) unsigned short Bh[64][40],  Bl[64][40];
    const int tid  = threadIdx.x;
    const int wave = tid >> 6, lane = tid & 63;
    const int l15 = lane & 15, l4 = lane >> 4;
    const int m0 = blockIdx.y * 128, n0 = blockIdx.x * 64;

    f32x4 acc[2][4];
#pragma unroll
    for (int rt = 0; rt < 2; ++rt)
#pragma unroll
        for (int ct = 0; ct < 4; ++ct) acc[rt][ct] = (f32x4){0.f, 0.f, 0.f, 0.f};

    const int ar  = tid >> 1;
    const int akc = (tid & 1) * 16;
    const int br  = tid >> 2;
    const int bkc = (tid & 3) * 8;

    for (int k0 = 0; k0 < K; k0 += 32) {
        {
            const size_t ab = (size_t)(m0 + ar) * K + k0 + akc;
            *(u16x8*)&Ah[ar][akc]     = *(const u16x8*)(Ahi + ab);
            *(u16x8*)&Ah[ar][akc + 8] = *(const u16x8*)(Ahi + ab + 8);
            *(u16x8*)&Al[ar][akc]     = *(const u16x8*)(Alo + ab);
            *(u16x8*)&Al[ar][akc + 8] = *(const u16x8*)(Alo + ab + 8);
            const size_t bb = (size_t)(n0 + br) * K + k0 + bkc;
            *(u16x8*)&Bh[br][bkc] = *(const u16x8*)(BThi + bb);
            *(u16x8*)&Bl[br][bkc] = *(const u16x8*)(BTlo + bb);
        }
        __syncthreads();

        const int kk = l4 * 8;
        bf16x8 ah[2], al[2], bh[4], bl[4];
#pragma unroll
        for (int rt = 0; rt < 2; ++rt) {
            const int r = wave * 32 + rt * 16 + l15;
            ah[rt] = *(const bf16x8*)&Ah[r][kk];
            al[rt] = *(const bf16x8*)&Al[r][kk];
        }
#pragma unroll
        for (int ct = 0; ct < 4; ++ct) {
            const int n = ct * 16 + l15;
            bh[ct] = *(const bf16x8*)&Bh[n][kk];
            bl[ct] = *(const bf16x8*)&Bl[n][kk];
        }
#pragma unroll
        for (int rt = 0; rt < 2; ++rt)
#pragma unroll
            for (int ct = 0; ct < 4; ++ct) {
                acc[rt][ct] = __builtin_amdgcn_mfma_f32_16x16x32_bf16(ah[rt], bh[ct], acc[rt][ct], 0, 0, 0);
                acc[rt][ct] = __builtin_amdgcn_mfma_f32_16x16x32_bf16(ah[rt], bl[ct], acc[rt][ct], 0, 0, 0);
                acc[rt][ct] = __builtin_amdgcn_mfma_f32_16x16x32_bf16(al[rt], bh[ct], acc[rt][ct], 0, 0, 0);
            }
        __syncthreads();
    }

#pragma unroll
    for (int rt = 0; rt < 2; ++rt) {
        const int rbase = m0 + wave * 32 + rt * 16 + l4 * 4;
#pragma unroll
        for (int ct = 0; ct < 4; ++ct) {
            const int cg = n0 + ct * 16 + l15;
            const float bv = bias[cg];
#pragma unroll
            for (int j = 0; j < 4; ++j) {
                const float v = acc[rt][ct][j] + bv;
                const size_t r = (size_t)(rbase + j);
                if constexpr (SEG == 0) {
                    C[r * NACT + cg] = v;
                } else {
                    if (cg < 256)      zbuf[r * DINNER + cg] = v;
                    else if (cg < 512) xbuf[r * DINNER + (cg - 256)] = v;
                    else if (cg < 640) bcbuf[r * BCW2 + (cg - 512)] = v;
                    else if (cg < NPROJ) dtcol[r * 4 + (cg - 640)] = v;
                }
            }
        }
    }
}

// ---------------------------------------------------------------------------
__global__ void make_wc(const float* __restrict__ W_enc, const float* __restrict__ W_in,
                        const float* __restrict__ b_enc,
                        unsigned short* __restrict__ WcThi, unsigned short* __restrict__ WcTlo,
                        float* __restrict__ bz)
{
    const int n = blockIdx.x;
    const int r = threadIdx.x;
    float v = 0.f;
    if (n < NPROJ)
        for (int k = 0; k < DMODEL; ++k)
            v = fmaf(W_enc[r * DMODEL + k], W_in[k * NPROJ + n], v);
    unsigned short hi, lo; splitbf(v, hi, lo);
    WcThi[n * OBSD + r] = hi;
    WcTlo[n * OBSD + r] = lo;
    if (r == 0) {
        float bv = 0.f;
        if (n < NPROJ)
            for (int k = 0; k < DMODEL; ++k)
                bv = fmaf(b_enc[k], W_in[k * NPROJ + n], bv);
        bz[n] = bv;
    }
}

// ---------------------------------------------------------------------------
__global__ void fuse_whead(const float* __restrict__ W_out, const float* __restrict__ W_act,
                           const float* __restrict__ W_val, const float* __restrict__ norm_w,
                           unsigned short* __restrict__ WhThi, unsigned short* __restrict__ WhTlo,
                           float* __restrict__ Wv)
{
    const int k = blockIdx.x;
    const int j = threadIdx.x;
    float s = 0.f;
    for (int m = 0; m < DMODEL; ++m)
        s = fmaf(W_out[k * DMODEL + m], W_act[m * NACT + j], s);
    s *= norm_w[k];
    unsigned short hi, lo; splitbf(s, hi, lo);
    WhThi[j * DINNER + k] = hi;
    WhTlo[j * DINNER + k] = lo;
    if (j == 0) {
        float sv = 0.f;
        for (int m = 0; m < DMODEL; ++m)
            sv = fmaf(W_out[k * DMODEL + m], W_val[m], sv);
        Wv[k] = sv * norm_w[k];
    }
}

// ---------------------------------------------------------------------------
__global__ void conv_obs(const float* __restrict__ obs,
                         unsigned short* __restrict__ Ahi, unsigned short* __restrict__ Alo)
{
    const size_t total = (size_t)NTOK * OBSD / 4;
    for (size_t i = (size_t)blockIdx.x * blockDim.x + threadIdx.x; i < total;
         i += (size_t)gridDim.x * blockDim.x) {
        const float4 v = ((const float4*)obs)[i];
        u16x4 h, l;
        splitbf(v.x, ((unsigned short*)&h)[0], ((unsigned short*)&l)[0]);
        splitbf(v.y, ((unsigned short*)&h)[1], ((unsigned short*)&l)[1]);
        splitbf(v.z, ((unsigned short*)&h)[2], ((unsigned short*)&l)[2]);
        splitbf(v.w, ((unsigned short*)&h)[3], ((unsigned short*)&l)[3]);
        ((u16x4*)Ahi)[i] = h;
        ((u16x4*)Alo)[i] = l;
    }
}

// ---------------------------------------------------------------------------
__global__ void prep_scan(const float* __restrict__ dtcol, const float* __restrict__ dt_bias,
                          const float* __restrict__ A_log,
                          float* __restrict__ dtT, float* __restrict__ laT,
                          float* __restrict__ dApbuf)
{
    const int bc = blockIdx.x;
    const int bh = bc >> 6, c = bc & 63;
    const int b = bh >> 2, h = bh & 3;
    const int lane = threadIdx.x;
    const size_t tok = (size_t)b * TSEQ + c * CHUNK + lane;
    const float x = dtcol[tok * 4 + h] + dt_bias[h];
    const float dt = (x > 20.f) ? x : log1pf(expf(x));
    const float A = -expf(A_log[h]);
    float v = dt * A;
#pragma unroll
    for (int d = 1; d < 64; d <<= 1) {
        const float o = __shfl_up(v, d, 64);
        if (lane >= d) v += o;
    }
    const size_t o = (size_t)bh * TSEQ + c * CHUNK + lane;
    dtT[o] = dt;
    laT[o] = v;
    if (lane == 63) dApbuf[bh * NCHUNK + c] = __expf(v);
}

// ---------------------------------------------------------------------------
// Phase A: chunk-local states via GEMM (fp32 VALU — passed r9/r10).
// ---------------------------------------------------------------------------
__launch_bounds__(256)
__global__ void scan_state(const float* __restrict__ xbuf, const float* __restrict__ bcbuf,
                           const float* __restrict__ dtT, const float* __restrict__ laT,
                           const float* __restrict__ W_conv, const float* __restrict__ b_conv,
                           float* __restrict__ states)
{
    __shared__ float Xs[CHUNK][LP];
    __shared__ float Bw[CHUNK][LP];
    __shared__ float w_l[CHUNK];
    const int c = blockIdx.x, bh = blockIdx.y;
    const int b = bh >> 2, h = bh & 3;
    const int tid = threadIdx.x;
    const size_t row0 = (size_t)b * TSEQ;
    const int tb = c * CHUNK;

    if (tid < CHUNK) {
        const size_t o = (size_t)bh * TSEQ + tb;
        const float laLast = laT[o + CHUNK - 1];
        w_l[tid] = dtT[o + tid] * __expf(laLast - laT[o + tid]);
    }
    __syncthreads();

    const int sg = tid & 15, st = tid >> 4;
    const int t4 = st * 4;

    {
        const int ch = h * HEADDIM + sg * 4;
        float w[4][4], bb[4];
#pragma unroll
        for (int j = 0; j < 4; ++j) {
            bb[j] = b_conv[ch + j];
#pragma unroll
            for (int k = 0; k < 4; ++k) w[j][k] = W_conv[(ch + j) * 4 + k];
        }
        float rx[4][7];
#pragma unroll
        for (int r = 0; r < 7; ++r) {
            const int tg = tb + t4 - 3 + r;
            float4 v = make_float4(0.f, 0.f, 0.f, 0.f);
            if (tg >= 0) v = *(const float4*)(xbuf + (row0 + tg) * DINNER + ch);
            rx[0][r] = v.x; rx[1][r] = v.y; rx[2][r] = v.z; rx[3][r] = v.w;
        }
#pragma unroll
        for (int i = 0; i < 4; ++i) {
            float o[4];
#pragma unroll
            for (int j = 0; j < 4; ++j)
                o[j] = siluf(fmaf(rx[j][i + 3], w[j][3], fmaf(rx[j][i + 2], w[j][2],
                             fmaf(rx[j][i + 1], w[j][1], fmaf(rx[j][i], w[j][0], bb[j])))));
            *(float4*)&Xs[t4 + i][sg * 4] = make_float4(o[0], o[1], o[2], o[3]);
        }
    }
    {
        const int ch = sg * 4;
        float w[4][4], bb[4];
#pragma unroll
        for (int j = 0; j < 4; ++j) {
            bb[j] = b_conv[DINNER + ch + j];
#pragma unroll
            for (int k = 0; k < 4; ++k) w[j][k] = W_conv[(DINNER + ch + j) * 4 + k];
        }
        float rx[4][7];
#pragma unroll
        for (int r = 0; r < 7; ++r) {
            const int tg = tb + t4 - 3 + r;
            float4 v = make_float4(0.f, 0.f, 0.f, 0.f);
            if (tg >= 0) v = *(const float4*)(bcbuf + (row0 + tg) * BCW2 + ch);
            rx[0][r] = v.x; rx[1][r] = v.y; rx[2][r] = v.z; rx[3][r] = v.w;
        }
#pragma unroll
        for (int i = 0; i < 4; ++i) {
            const float wi = w_l[t4 + i];
            float o[4];
#pragma unroll
            for (int j = 0; j < 4; ++j)
                o[j] = wi * siluf(fmaf(rx[j][i + 3], w[j][3], fmaf(rx[j][i + 2], w[j][2],
                              fmaf(rx[j][i + 1], w[j][1], fmaf(rx[j][i], w[j][0], bb[j])))));
            *(float4*)&Bw[t4 + i][sg * 4] = make_float4(o[0], o[1], o[2], o[3]);
        }
    }
    __syncthreads();

    const int pn = tid & 15, pp = tid >> 4;
    const int n4 = pn * 4, p4 = pp * 4;
    float acc[4][4];
#pragma unroll
    for (int a = 0; a < 4; ++a)
#pragma unroll
        for (int d = 0; d < 4; ++d) acc[a][d] = 0.f;
#pragma unroll 4
    for (int i = 0; i < CHUNK; ++i) {
        const float4 xv = *(const float4*)&Xs[i][p4];
        const float4 bv = *(const float4*)&Bw[i][n4];
        const float xa[4] = {xv.x, xv.y, xv.z, xv.w};
        const float ba[4] = {bv.x, bv.y, bv.z, bv.w};
#pragma unroll
        for (int a = 0; a < 4; ++a)
#pragma unroll
            for (int d = 0; d < 4; ++d) acc[a][d] = fmaf(xa[a], ba[d], acc[a][d]);
    }
    const size_t so = (size_t)(bh * NCHUNK + c) * 4096;
#pragma unroll
    for (int a = 0; a < 4; ++a)
        *(float4*)(states + so + (size_t)(p4 + a) * 64 + n4) =
            make_float4(acc[a][0], acc[a][1], acc[a][2], acc[a][3]);
}

// ---------------------------------------------------------------------------
__global__ void chunk_scan(float* __restrict__ states, const float* __restrict__ dAprod)
{
    __shared__ float sdA[NCHUNK];
    const int bh = blockIdx.x >> 4;
    const int elem = ((blockIdx.x & 15) << 8) | threadIdx.x;
    if (threadIdx.x < NCHUNK) sdA[threadIdx.x] = dAprod[bh * NCHUNK + threadIdx.x];
    __syncthreads();
    const size_t base = (size_t)bh * NCHUNK * 4096 + elem;
    float s0 = 0.f;
    for (int c = 0; c < NCHUNK; ++c) {
        const size_t off = base + (size_t)c * 4096;
        const float Sc = states[off];
        states[off] = s0;
        s0 = fmaf(sdA[c], s0, Sc);
    }
}

// ---------------------------------------------------------------------------
// Phase B: outputs via 3 fp32 micro-GEMMs per (bh, chunk) (r10-verified).
// ---------------------------------------------------------------------------
__launch_bounds__(256)
__global__ void scan_out(const float* __restrict__ xbuf, const float* __restrict__ bcbuf,
                         float* zbuf,
                         const float* __restrict__ dtT, const float* __restrict__ laT,
                         const float* __restrict__ W_conv, const float* __restrict__ b_conv,
                         const float* __restrict__ Dparam,
                         const float* __restrict__ states)
{
    __shared__ float BcT[CHUNK][LP];
    __shared__ float CcT[CHUNK][LP];
    __shared__ float Xs[CHUNK][LP];
    __shared__ float la_l[CHUNK], dt_l[CHUNK], a_l[CHUNK];
    float (*ST)[LP] = BcT;
    float (*MT)[LP] = CcT;

    const int c = blockIdx.x, bh = blockIdx.y;
    const int b = bh >> 2, h = bh & 3;
    const int tid = threadIdx.x;
    const size_t row0 = (size_t)b * TSEQ;
    const int tb = c * CHUNK;
    const float Dh = Dparam[h];

    const int pS = tid >> 2;
    const int n16 = (tid & 3) * 16;
    const float* Sg = states + (size_t)(bh * NCHUNK + c) * 4096 + (size_t)pS * 64 + n16;
    const float4 sv0 = *(const float4*)(Sg + 0);
    const float4 sv1 = *(const float4*)(Sg + 4);
    const float4 sv2 = *(const float4*)(Sg + 8);
    const float4 sv3 = *(const float4*)(Sg + 12);

    if (tid < CHUNK) {
        const size_t o = (size_t)bh * TSEQ + tb + tid;
        const float la = laT[o];
        la_l[tid] = la;
        dt_l[tid] = dtT[o];
        a_l[tid] = __expf(la);
    }

    const int sg = tid & 15, st = tid >> 4;
    const int t4s = st * 4;

    {
        const int ch = h * HEADDIM + sg * 4;
        float w[4][4], bb[4];
#pragma unroll
        for (int j = 0; j < 4; ++j) {
            bb[j] = b_conv[ch + j];
#pragma unroll
            for (int k = 0; k < 4; ++k) w[j][k] = W_conv[(ch + j) * 4 + k];
        }
        float rx[4][7];
#pragma unroll
        for (int r = 0; r < 7; ++r) {
            const int tg = tb + t4s - 3 + r;
            float4 v = make_float4(0.f, 0.f, 0.f, 0.f);
            if (tg >= 0) v = *(const float4*)(xbuf + (row0 + tg) * DINNER + ch);
            rx[0][r] = v.x; rx[1][r] = v.y; rx[2][r] = v.z; rx[3][r] = v.w;
        }
#pragma unroll
        for (int i = 0; i < 4; ++i) {
            float o[4];
#pragma unroll
            for (int j = 0; j < 4; ++j)
                o[j] = siluf(fmaf(rx[j][i + 3], w[j][3], fmaf(rx[j][i + 2], w[j][2],
                             fmaf(rx[j][i + 1], w[j][1], fmaf(rx[j][i], w[j][0], bb[j])))));
            *(float4*)&Xs[t4s + i][sg * 4] = make_float4(o[0], o[1], o[2], o[3]);
        }
    }
    {
        const int ch = sg * 4;
        float w[4][4], bb[4];
#pragma unroll
        for (int j = 0; j < 4; ++j) {
            bb[j] = b_conv[DINNER + ch + j];
#pragma unroll
            for (int k = 0; k < 4; ++k) w[j][k] = W_conv[(DINNER + ch + j) * 4 + k];
        }
        float rx[4][7];
#pragma unroll
        for (int r = 0; r < 7; ++r) {
            const int tg = tb + t4s - 3 + r;
            float4 v = make_float4(0.f, 0.f, 0.f, 0.f);
            if (tg >= 0) v = *(const float4*)(bcbuf + (row0 + tg) * BCW2 + ch);
            rx[0][r] = v.x; rx[1][r] = v.y; rx[2][r] = v.z; rx[3][r] = v.w;
        }
#pragma unroll
        for (int j = 0; j < 4; ++j) {
            float o[4];
#pragma unroll
            for (int i = 0; i < 4; ++i)
                o[i] = siluf(fmaf(rx[j][i + 3], w[j][3], fmaf(rx[j][i + 2], w[j][2],
                             fmaf(rx[j][i + 1], w[j][1], fmaf(rx[j][i], w[j][0], bb[j])))));
            *(float4*)&BcT[ch + j][t4s] = make_float4(o[0], o[1], o[2], o[3]);
        }
    }
    {
        const int ch = sg * 4;
        float w[4][4], bb[4];
#pragma unroll
        for (int j = 0; j < 4; ++j) {
            bb[j] = b_conv[DINNER + 64 + ch + j];
#pragma unroll
            for (int k = 0; k < 4; ++k) w[j][k] = W_conv[(DINNER + 64 + ch + j) * 4 + k];
        }
        float rx[4][7];
#pragma unroll
        for (int r = 0; r < 7; ++r) {
            const int tg = tb + t4s - 3 + r;
            float4 v = make_float4(0.f, 0.f, 0.f, 0.f);
            if (tg >= 0) v = *(const float4*)(bcbuf + (row0 + tg) * BCW2 + 64 + ch);
            rx[0][r] = v.x; rx[1][r] = v.y; rx[2][r] = v.z; rx[3][r] = v.w;
        }
#pragma unroll
        for (int j = 0; j < 4; ++j) {
            float o[4];
#pragma unroll
            for (int i = 0; i < 4; ++i)
                o[i] = siluf(fmaf(rx[j][i + 3], w[j][3], fmaf(rx[j][i + 2], w[j][2],
                             fmaf(rx[j][i + 1], w[j][1], fmaf(rx[j][i], w[j][0], bb[j])))));
            *(float4*)&CcT[ch + j][t4s] = make_float4(o[0], o[1], o[2], o[3]);
        }
    }
    __syncthreads();

    const int ti = tid & 15, tt = tid >> 4;
    const int i4 = ti * 4, t4 = tt * 4;

    float m[4][4];
#pragma unroll
    for (int a = 0; a < 4; ++a)
#pragma unroll
        for (int d = 0; d < 4; ++d) m[a][d] = 0.f;
#pragma unroll 4
    for (int n = 0; n < 64; ++n) {
        const float4 cv = *(const float4*)&CcT[n][t4];
        const float4 bv = *(const float4*)&BcT[n][i4];
        const float ca[4] = {cv.x, cv.y, cv.z, cv.w};
        const float ba[4] = {bv.x, bv.y, bv.z, bv.w};
#pragma unroll
        for (int a = 0; a < 4; ++a)
#pragma unroll
            for (int d = 0; d < 4; ++d) m[a][d] = fmaf(ca[a], ba[d], m[a][d]);
    }
    {
        float lat[4], lai[4], dti[4];
#pragma unroll
        for (int a = 0; a < 4; ++a) lat[a] = la_l[t4 + a];
#pragma unroll
        for (int d = 0; d < 4; ++d) { lai[d] = la_l[i4 + d]; dti[d] = dt_l[i4 + d]; }
#pragma unroll
        for (int a = 0; a < 4; ++a)
#pragma unroll
            for (int d = 0; d < 4; ++d) {
                if (i4 + d <= t4 + a)
                    m[a][d] = m[a][d] * dti[d] * __expf(lat[a] - lai[d]);
                else
                    m[a][d] = 0.f;
            }
    }
    __syncthreads();

    {
        const float sa[16] = {sv0.x, sv0.y, sv0.z, sv0.w, sv1.x, sv1.y, sv1.z, sv1.w,
                              sv2.x, sv2.y, sv2.z, sv2.w, sv3.x, sv3.y, sv3.z, sv3.w};
#pragma unroll
        for (int q = 0; q < 16; ++q) ST[n16 + q][pS] = sa[q];
    }
    __syncthreads();

    float y2[4][4];
#pragma unroll
    for (int a = 0; a < 4; ++a)
#pragma unroll
        for (int d = 0; d < 4; ++d) y2[a][d] = 0.f;
#pragma unroll 4
    for (int n = 0; n < 64; ++n) {
        const float4 cv = *(const float4*)&CcT[n][t4];
        const float4 sv = *(const float4*)&ST[n][i4];
        const float ca[4] = {cv.x, cv.y, cv.z, cv.w};
        const float sa[4] = {sv.x, sv.y, sv.z, sv.w};
#pragma unroll
        for (int a = 0; a < 4; ++a)
#pragma unroll
            for (int d = 0; d < 4; ++d) y2[a][d] = fmaf(ca[a], sa[d], y2[a][d]);
    }
    __syncthreads();

#pragma unroll
    for (int d = 0; d < 4; ++d)
        *(float4*)&MT[i4 + d][t4] = make_float4(m[0][d], m[1][d], m[2][d], m[3][d]);
    __syncthreads();

    float yac[4][4];
#pragma unroll
    for (int a = 0; a < 4; ++a)
#pragma unroll
        for (int d = 0; d < 4; ++d) yac[a][d] = 0.f;
#pragma unroll 4
    for (int k = 0; k < CHUNK; ++k) {
        const float4 mv = *(const float4*)&MT[k][t4];
        const float4 xv = *(const float4*)&Xs[k][i4];
        const float ma[4] = {mv.x, mv.y, mv.z, mv.w};
        const float xa[4] = {xv.x, xv.y, xv.z, xv.w};
#pragma unroll
        for (int a = 0; a < 4; ++a)
#pragma unroll
            for (int d = 0; d < 4; ++d) yac[a][d] = fmaf(ma[a], xa[d], yac[a][d]);
    }

#pragma unroll
    for (int a = 0; a < 4; ++a) {
        const int t = t4 + a;
        const float at = a_l[t];
        const float4 xv = *(const float4*)&Xs[t][i4];
        const float xa[4] = {xv.x, xv.y, xv.z, xv.w};
        float* zp = zbuf + (row0 + tb + t) * DINNER + h * HEADDIM + i4;
        const float4 zv = *(const float4*)zp;
        const float za[4] = {zv.x, zv.y, zv.z, zv.w};
        float g[4];
#pragma unroll
        for (int d = 0; d < 4; ++d) {
            const float Y = yac[a][d] + at * y2[a][d] + Dh * xa[d];
            g[d] = Y * siluf(za[d]);
        }
        *(float4*)zp = make_float4(g[0], g[1], g[2], g[3]);
    }
}

// ---------------------------------------------------------------------------
__launch_bounds__(256)
__global__ void rms_val(const float* __restrict__ g, const float* __restrict__ Wv,
                        const float* __restrict__ bval, float* __restrict__ values,
                        unsigned short* __restrict__ Ghi, unsigned short* __restrict__ Glo)
{
    const size_t tok = (size_t)blockIdx.x * 4 + (threadIdx.x >> 6);
    const int lane = threadIdx.x & 63;
    const float4 v = *(const float4*)(g + tok * DINNER + lane * 4);
    const float4 w = *(const float4*)(Wv + lane * 4);
    float ssq = v.x * v.x + v.y * v.y + v.z * v.z + v.w * v.w;
    float gw  = v.x * w.x + v.y * w.y + v.z * w.z + v.w * w.w;
#pragma unroll
    for (int d = 1; d < 64; d <<= 1) {
        ssq += __shfl_xor(ssq, d, 64);
        gw  += __shfl_xor(gw, d, 64);
    }
    const float rms = rsqrtf(ssq * (1.f / DINNER) + 1e-5f);
    u16x4 h, l;
    splitbf(v.x * rms, ((unsigned short*)&h)[0], ((unsigned short*)&l)[0]);
    splitbf(v.y * rms, ((unsigned short*)&h)[1], ((unsigned short*)&l)[1]);
    splitbf(v.z * rms, ((unsigned short*)&h)[2], ((unsigned short*)&l)[2]);
    splitbf(v.w * rms, ((unsigned short*)&h)[3], ((unsigned short*)&l)[3]);
    *(u16x4*)(Ghi + tok * DINNER + lane * 4) = h;
    *(u16x4*)(Glo + tok * DINNER + lane * 4) = l;
    if (lane == 0) values[tok] = gw * rms + bval[0];
}

// ---------------------------------------------------------------------------
extern "C" void kernel_launch(void* const* d_in, const int* in_sizes, int n_in,
                              void* d_out, int out_size, void* d_ws, size_t ws_size,
                              hipStream_t stream)
{
    (void)in_sizes; (void)n_in; (void)out_size; (void)ws_size;
    const float* obs     = (const float*)d_in[0];
    const float* W_enc   = (const float*)d_in[1];
    const float* b_enc   = (const float*)d_in[2];
    const float* W_in    = (const float*)d_in[3];
    const float* W_conv  = (const float*)d_in[4];
    const float* b_conv  = (const float*)d_in[5];
    const float* dt_bias = (const float*)d_in[6];
    const float* A_log   = (const float*)d_in[7];
    const float* Dp      = (const float*)d_in[8];
    const float* norm_w  = (const float*)d_in[9];
    const float* W_out   = (const float*)d_in[10];
    const float* W_act   = (const float*)d_in[11];
    const float* b_act   = (const float*)d_in[12];
    const float* W_val   = (const float*)d_in[13];
    const float* b_val   = (const float*)d_in[14];

    float* logits = (float*)d_out;
    float* values = logits + (size_t)NTOK * NACT;

    char* ws = (char*)d_ws;
    size_t off = 0;
    auto alloc = [&](size_t nbytes) {
        char* ptr = ws + off;
        off += (nbytes + 255) / 256 * 256;
        return ptr;
    };
    float* zbuf   = (float*)alloc((size_t)NTOK * DINNER * 4);   // z -> g in place
    float* xbuf   = (float*)alloc((size_t)NTOK * DINNER * 4);
    float* bcbuf  = (float*)alloc((size_t)NTOK * BCW2 * 4);
    float* dtcol  = (float*)alloc((size_t)NTOK * 4 * 4);
    // shared 134.2 MB region: obs-bf16 (3-4) -> states (5-8) -> g-bf16 (9-10)
    char*  shared = alloc((size_t)NTOK * OBSD * 2 * 2);
    unsigned short* Ahi = (unsigned short*)shared;
    unsigned short* Alo = Ahi + (size_t)NTOK * OBSD;
    float* states = (float*)shared;
    unsigned short* Ghi = (unsigned short*)shared;
    unsigned short* Glo = Ghi + (size_t)NTOK * DINNER;
    float* dtT    = (float*)alloc((size_t)NBATCH * NHEADS * TSEQ * 4);
    float* laT    = (float*)alloc((size_t)NBATCH * NHEADS * TSEQ * 4);
    float* dApb   = (float*)alloc(NBATCH * NHEADS * NCHUNK * 4);
    unsigned short* WcThi = (unsigned short*)alloc((size_t)NPPAD * OBSD * 2);
    unsigned short* WcTlo = (unsigned short*)alloc((size_t)NPPAD * OBSD * 2);
    float* bz     = (float*)alloc(NPPAD * 4);
    unsigned short* WhThi = (unsigned short*)alloc((size_t)NACT * DINNER * 2);
    unsigned short* WhTlo = (unsigned short*)alloc((size_t)NACT * DINNER * 2);
    float* Wv     = (float*)alloc(DINNER * 4);

    fuse_whead<<<DINNER, NACT, 0, stream>>>(W_out, W_act, W_val, norm_w, WhThi, WhTlo, Wv);
    make_wc<<<NPPAD, 256, 0, stream>>>(W_enc, W_in, b_enc, WcThi, WcTlo, bz);
    conv_obs<<<2048, 256, 0, stream>>>(obs, Ahi, Alo);
    mfma_gemm<1><<<dim3(NPPAD / 64, NTOK / 128), 256, 0, stream>>>(
        Ahi, Alo, WcThi, WcTlo, OBSD, bz, nullptr, zbuf, xbuf, bcbuf, dtcol);
    prep_scan<<<NBATCH * NHEADS * NCHUNK, 64, 0, stream>>>(
        dtcol, dt_bias, A_log, dtT, laT, dApb);
    scan_state<<<dim3(NCHUNK, NBATCH * NHEADS), 256, 0, stream>>>(
        xbuf, bcbuf, dtT, laT, W_conv, b_conv, states);
    chunk_scan<<<NBATCH * NHEADS * 16, 256, 0, stream>>>(states, dApb);
    scan_out<<<dim3(NCHUNK, NBATCH * NHEADS), 256, 0, stream>>>(
        xbuf, bcbuf, zbuf, dtT, laT, W_conv, b_conv, Dp, states);
    rms_val<<<NTOK / 4, 256, 0, stream>>>(zbuf, Wv, b_val, values, Ghi, Glo);
    mfma_gemm<0><<<dim3(1, NTOK / 128), 256, 0, stream>>>(
        Ghi, Glo, WhThi, WhTlo, DINNER, b_act, logits, nullptr, nullptr, nullptr, nullptr);
}

// Round 18
// 832.652 us; speedup vs baseline: 1.4121x; 1.0200x over previous
//
#include <hip/hip_runtime.h>
#include <math.h>

#define OBSD   256
#define TSEQ   4096
#define NBATCH 32
#define DMODEL 128
#define DSTATE 64
#define DINNER 256
#define NHEADS 4
#define HEADDIM 64
#define NPROJ  644
#define NPPAD  704   // in_proj N padded to 11*64
#define NTOK   (NBATCH*TSEQ)
#define CHUNK  64
#define NCHUNK (TSEQ/CHUNK)
#define NACT   64
#define BCW2   128   // bcbuf row width (B 64 | C 64)
#define LP     68    // padded LDS row stride (scan kernels)

typedef __attribute__((ext_vector_type(8))) short bf16x8;
typedef __attribute__((ext_vector_type(4))) float f32x4;
typedef __attribute__((ext_vector_type(8))) unsigned short u16x8;
typedef __attribute__((ext_vector_type(4))) unsigned short u16x4;

__device__ __forceinline__ float siluf(float x) { return x / (1.f + __expf(-x)); }

// round-to-nearest-even bf16 (bit pattern) and hi/lo split: v ~= hi + lo
__device__ __forceinline__ unsigned short bfhi(float v) {
    unsigned u = __float_as_uint(v);
    return (unsigned short)((u + 0x7FFFu + ((u >> 16) & 1u)) >> 16);
}
__device__ __forceinline__ void splitbf(float v, unsigned short& hi, unsigned short& lo) {
    hi = bfhi(v);
    const float hf = __uint_as_float((unsigned)hi << 16);
    lo = bfhi(v - hf);
}

// ---------------------------------------------------------------------------
// Split-bf16 MFMA GEMM (HW-verified round 10).
// ---------------------------------------------------------------------------
template<int SEG>
__launch_bounds__(256)
__global__ void mfma_gemm(const unsigned short* __restrict__ Ahi,
                          const unsigned short* __restrict__ Alo,
                          const unsigned short* __restrict__ BThi,
                          const unsigned short* __restrict__ BTlo,
                          int K, const float* __restrict__ bias,
                          float* __restrict__ C,
                          float* __restrict__ zbuf, float* __restrict__ xbuf,
                          float* __restrict__ bcbuf, float* __restrict__ dtcol)
{
    __shared__ __align__(16) unsigned short Ah[128][40], Al[128][40];
    __shared__ __align__(16) unsigned short Bh[64][40],  Bl[64][40];
    const int tid  = threadIdx.x;
    const int wave = tid >> 6, lane = tid & 63;
    const int l15 = lane & 15, l4 = lane >> 4;
    const int m0 = blockIdx.y * 128, n0 = blockIdx.x * 64;

    f32x4 acc[2][4];
#pragma unroll
    for (int rt = 0; rt < 2; ++rt)
#pragma unroll
        for (int ct = 0; ct < 4; ++ct) acc[rt][ct] = (f32x4){0.f, 0.f, 0.f, 0.f};

    const int ar  = tid >> 1;
    const int akc = (tid & 1) * 16;
    const int br  = tid >> 2;
    const int bkc = (tid & 3) * 8;

    for (int k0 = 0; k0 < K; k0 += 32) {
        {
            const size_t ab = (size_t)(m0 + ar) * K + k0 + akc;
            *(u16x8*)&Ah[ar][akc]     = *(const u16x8*)(Ahi + ab);
            *(u16x8*)&Ah[ar][akc + 8] = *(const u16x8*)(Ahi + ab + 8);
            *(u16x8*)&Al[ar][akc]     = *(const u16x8*)(Alo + ab);
            *(u16x8*)&Al[ar][akc + 8] = *(const u16x8*)(Alo + ab + 8);
            const size_t bb = (size_t)(n0 + br) * K + k0 + bkc;
            *(u16x8*)&Bh[br][bkc] = *(const u16x8*)(BThi + bb);
            *(u16x8*)&Bl[br][bkc] = *(const u16x8*)(BTlo + bb);
        }
        __syncthreads();

        const int kk = l4 * 8;
        bf16x8 ah[2], al[2], bh[4], bl[4];
#pragma unroll
        for (int rt = 0; rt < 2; ++rt) {
            const int r = wave * 32 + rt * 16 + l15;
            ah[rt] = *(const bf16x8*)&Ah[r][kk];
            al[rt] = *(const bf16x8*)&Al[r][kk];
        }
#pragma unroll
        for (int ct = 0; ct < 4; ++ct) {
            const int n = ct * 16 + l15;
            bh[ct] = *(const bf16x8*)&Bh[n][kk];
            bl[ct] = *(const bf16x8*)&Bl[n][kk];
        }
#pragma unroll
        for (int rt = 0; rt < 2; ++rt)
#pragma unroll
            for (int ct = 0; ct < 4; ++ct) {
                acc[rt][ct] = __builtin_amdgcn_mfma_f32_16x16x32_bf16(ah[rt], bh[ct], acc[rt][ct], 0, 0, 0);
                acc[rt][ct] = __builtin_amdgcn_mfma_f32_16x16x32_bf16(ah[rt], bl[ct], acc[rt][ct], 0, 0, 0);
                acc[rt][ct] = __builtin_amdgcn_mfma_f32_16x16x32_bf16(al[rt], bh[ct], acc[rt][ct], 0, 0, 0);
            }
        __syncthreads();
    }

#pragma unroll
    for (int rt = 0; rt < 2; ++rt) {
        const int rbase = m0 + wave * 32 + rt * 16 + l4 * 4;
#pragma unroll
        for (int ct = 0; ct < 4; ++ct) {
            const int cg = n0 + ct * 16 + l15;
            const float bv = bias[cg];
#pragma unroll
            for (int j = 0; j < 4; ++j) {
                const float v = acc[rt][ct][j] + bv;
                const size_t r = (size_t)(rbase + j);
                if constexpr (SEG == 0) {
                    C[r * NACT + cg] = v;
                } else {
                    if (cg < 256)      zbuf[r * DINNER + cg] = v;
                    else if (cg < 512) xbuf[r * DINNER + (cg - 256)] = v;
                    else if (cg < 640) bcbuf[r * BCW2 + (cg - 512)] = v;
                    else if (cg < NPROJ) dtcol[r * 4 + (cg - 640)] = v;
                }
            }
        }
    }
}

// ---------------------------------------------------------------------------
__global__ void make_wc(const float* __restrict__ W_enc, const float* __restrict__ W_in,
                        const float* __restrict__ b_enc,
                        unsigned short* __restrict__ WcThi, unsigned short* __restrict__ WcTlo,
                        float* __restrict__ bz)
{
    const int n = blockIdx.x;
    const int r = threadIdx.x;
    float v = 0.f;
    if (n < NPROJ)
        for (int k = 0; k < DMODEL; ++k)
            v = fmaf(W_enc[r * DMODEL + k], W_in[k * NPROJ + n], v);
    unsigned short hi, lo; splitbf(v, hi, lo);
    WcThi[n * OBSD + r] = hi;
    WcTlo[n * OBSD + r] = lo;
    if (r == 0) {
        float bv = 0.f;
        if (n < NPROJ)
            for (int k = 0; k < DMODEL; ++k)
                bv = fmaf(b_enc[k], W_in[k * NPROJ + n], bv);
        bz[n] = bv;
    }
}

// ---------------------------------------------------------------------------
__global__ void fuse_whead(const float* __restrict__ W_out, const float* __restrict__ W_act,
                           const float* __restrict__ W_val, const float* __restrict__ norm_w,
                           unsigned short* __restrict__ WhThi, unsigned short* __restrict__ WhTlo,
                           float* __restrict__ Wv)
{
    const int k = blockIdx.x;
    const int j = threadIdx.x;
    float s = 0.f;
    for (int m = 0; m < DMODEL; ++m)
        s = fmaf(W_out[k * DMODEL + m], W_act[m * NACT + j], s);
    s *= norm_w[k];
    unsigned short hi, lo; splitbf(s, hi, lo);
    WhThi[j * DINNER + k] = hi;
    WhTlo[j * DINNER + k] = lo;
    if (j == 0) {
        float sv = 0.f;
        for (int m = 0; m < DMODEL; ++m)
            sv = fmaf(W_out[k * DMODEL + m], W_val[m], sv);
        Wv[k] = sv * norm_w[k];
    }
}

// ---------------------------------------------------------------------------
__global__ void conv_obs(const float* __restrict__ obs,
                         unsigned short* __restrict__ Ahi, unsigned short* __restrict__ Alo)
{
    const size_t total = (size_t)NTOK * OBSD / 4;
    for (size_t i = (size_t)blockIdx.x * blockDim.x + threadIdx.x; i < total;
         i += (size_t)gridDim.x * blockDim.x) {
        const float4 v = ((const float4*)obs)[i];
        u16x4 h, l;
        splitbf(v.x, ((unsigned short*)&h)[0], ((unsigned short*)&l)[0]);
        splitbf(v.y, ((unsigned short*)&h)[1], ((unsigned short*)&l)[1]);
        splitbf(v.z, ((unsigned short*)&h)[2], ((unsigned short*)&l)[2]);
        splitbf(v.w, ((unsigned short*)&h)[3], ((unsigned short*)&l)[3]);
        ((u16x4*)Ahi)[i] = h;
        ((u16x4*)Alo)[i] = l;
    }
}

// ---------------------------------------------------------------------------
__global__ void prep_scan(const float* __restrict__ dtcol, const float* __restrict__ dt_bias,
                          const float* __restrict__ A_log,
                          float* __restrict__ dtT, float* __restrict__ laT,
                          float* __restrict__ dApbuf)
{
    const int bc = blockIdx.x;
    const int bh = bc >> 6, c = bc & 63;
    const int b = bh >> 2, h = bh & 3;
    const int lane = threadIdx.x;
    const size_t tok = (size_t)b * TSEQ + c * CHUNK + lane;
    const float x = dtcol[tok * 4 + h] + dt_bias[h];
    const float dt = (x > 20.f) ? x : log1pf(expf(x));
    const float A = -expf(A_log[h]);
    float v = dt * A;
#pragma unroll
    for (int d = 1; d < 64; d <<= 1) {
        const float o = __shfl_up(v, d, 64);
        if (lane >= d) v += o;
    }
    const size_t o = (size_t)bh * TSEQ + c * CHUNK + lane;
    dtT[o] = dt;
    laT[o] = v;
    if (lane == 63) dApbuf[bh * NCHUNK + c] = __expf(v);
}

// ---------------------------------------------------------------------------
// Phase A: chunk-local states via GEMM (fp32 VALU — passed r9/r10/r17).
// ---------------------------------------------------------------------------
__launch_bounds__(256)
__global__ void scan_state(const float* __restrict__ xbuf, const float* __restrict__ bcbuf,
                           const float* __restrict__ dtT, const float* __restrict__ laT,
                           const float* __restrict__ W_conv, const float* __restrict__ b_conv,
                           float* __restrict__ states)
{
    __shared__ float Xs[CHUNK][LP];
    __shared__ float Bw[CHUNK][LP];
    __shared__ float w_l[CHUNK];
    const int c = blockIdx.x, bh = blockIdx.y;
    const int b = bh >> 2, h = bh & 3;
    const int tid = threadIdx.x;
    const size_t row0 = (size_t)b * TSEQ;
    const int tb = c * CHUNK;

    if (tid < CHUNK) {
        const size_t o = (size_t)bh * TSEQ + tb;
        const float laLast = laT[o + CHUNK - 1];
        w_l[tid] = dtT[o + tid] * __expf(laLast - laT[o + tid]);
    }
    __syncthreads();

    const int sg = tid & 15, st = tid >> 4;
    const int t4 = st * 4;

    {
        const int ch = h * HEADDIM + sg * 4;
        float w[4][4], bb[4];
#pragma unroll
        for (int j = 0; j < 4; ++j) {
            bb[j] = b_conv[ch + j];
#pragma unroll
            for (int k = 0; k < 4; ++k) w[j][k] = W_conv[(ch + j) * 4 + k];
        }
        float rx[4][7];
#pragma unroll
        for (int r = 0; r < 7; ++r) {
            const int tg = tb + t4 - 3 + r;
            float4 v = make_float4(0.f, 0.f, 0.f, 0.f);
            if (tg >= 0) v = *(const float4*)(xbuf + (row0 + tg) * DINNER + ch);
            rx[0][r] = v.x; rx[1][r] = v.y; rx[2][r] = v.z; rx[3][r] = v.w;
        }
#pragma unroll
        for (int i = 0; i < 4; ++i) {
            float o[4];
#pragma unroll
            for (int j = 0; j < 4; ++j)
                o[j] = siluf(fmaf(rx[j][i + 3], w[j][3], fmaf(rx[j][i + 2], w[j][2],
                             fmaf(rx[j][i + 1], w[j][1], fmaf(rx[j][i], w[j][0], bb[j])))));
            *(float4*)&Xs[t4 + i][sg * 4] = make_float4(o[0], o[1], o[2], o[3]);
        }
    }
    {
        const int ch = sg * 4;
        float w[4][4], bb[4];
#pragma unroll
        for (int j = 0; j < 4; ++j) {
            bb[j] = b_conv[DINNER + ch + j];
#pragma unroll
            for (int k = 0; k < 4; ++k) w[j][k] = W_conv[(DINNER + ch + j) * 4 + k];
        }
        float rx[4][7];
#pragma unroll
        for (int r = 0; r < 7; ++r) {
            const int tg = tb + t4 - 3 + r;
            float4 v = make_float4(0.f, 0.f, 0.f, 0.f);
            if (tg >= 0) v = *(const float4*)(bcbuf + (row0 + tg) * BCW2 + ch);
            rx[0][r] = v.x; rx[1][r] = v.y; rx[2][r] = v.z; rx[3][r] = v.w;
        }
#pragma unroll
        for (int i = 0; i < 4; ++i) {
            const float wi = w_l[t4 + i];
            float o[4];
#pragma unroll
            for (int j = 0; j < 4; ++j)
                o[j] = wi * siluf(fmaf(rx[j][i + 3], w[j][3], fmaf(rx[j][i + 2], w[j][2],
                              fmaf(rx[j][i + 1], w[j][1], fmaf(rx[j][i], w[j][0], bb[j])))));
            *(float4*)&Bw[t4 + i][sg * 4] = make_float4(o[0], o[1], o[2], o[3]);
        }
    }
    __syncthreads();

    const int pn = tid & 15, pp = tid >> 4;
    const int n4 = pn * 4, p4 = pp * 4;
    float acc[4][4];
#pragma unroll
    for (int a = 0; a < 4; ++a)
#pragma unroll
        for (int d = 0; d < 4; ++d) acc[a][d] = 0.f;
#pragma unroll 4
    for (int i = 0; i < CHUNK; ++i) {
        const float4 xv = *(const float4*)&Xs[i][p4];
        const float4 bv = *(const float4*)&Bw[i][n4];
        const float xa[4] = {xv.x, xv.y, xv.z, xv.w};
        const float ba[4] = {bv.x, bv.y, bv.z, bv.w};
#pragma unroll
        for (int a = 0; a < 4; ++a)
#pragma unroll
            for (int d = 0; d < 4; ++d) acc[a][d] = fmaf(xa[a], ba[d], acc[a][d]);
    }
    const size_t so = (size_t)(bh * NCHUNK + c) * 4096;
#pragma unroll
    for (int a = 0; a < 4; ++a)
        *(float4*)(states + so + (size_t)(p4 + a) * 64 + n4) =
            make_float4(acc[a][0], acc[a][1], acc[a][2], acc[a][3]);
}

// ---------------------------------------------------------------------------
__global__ void chunk_scan(float* __restrict__ states, const float* __restrict__ dAprod)
{
    __shared__ float sdA[NCHUNK];
    const int bh = blockIdx.x >> 4;
    const int elem = ((blockIdx.x & 15) << 8) | threadIdx.x;
    if (threadIdx.x < NCHUNK) sdA[threadIdx.x] = dAprod[bh * NCHUNK + threadIdx.x];
    __syncthreads();
    const size_t base = (size_t)bh * NCHUNK * 4096 + elem;
    float s0 = 0.f;
    for (int c = 0; c < NCHUNK; ++c) {
        const size_t off = base + (size_t)c * 4096;
        const float Sc = states[off];
        states[off] = s0;
        s0 = fmaf(sdA[c], s0, Sc);
    }
}

// ---------------------------------------------------------------------------
// Phase B: outputs via 3 fp32 micro-GEMMs per (bh, chunk).
// r17 -> r18: LDS cut from 3 slots (53 KB) to 2 slots (36 KB): Xs now
// overlays the BcT slot (ST dead after GEMM3), staged between GEMM3 and
// GEMM2 alongside the MT write. Arithmetic is bit-identical to r17.
// Slot P = BcT -> ST -> Xs ;  Slot Q = CcT -> MT.
// ---------------------------------------------------------------------------
__launch_bounds__(256)
__global__ void scan_out(const float* __restrict__ xbuf, const float* __restrict__ bcbuf,
                         float* zbuf,
                         const float* __restrict__ dtT, const float* __restrict__ laT,
                         const float* __restrict__ W_conv, const float* __restrict__ b_conv,
                         const float* __restrict__ Dparam,
                         const float* __restrict__ states)
{
    __shared__ float BcT[CHUNK][LP];   // P: Bc[n][i] -> ST[n][p] -> Xs[t][p]
    __shared__ float CcT[CHUNK][LP];   // Q: Cc[n][t] -> MT[i][t]
    __shared__ float la_l[CHUNK], dt_l[CHUNK], a_l[CHUNK];
    float (*ST)[LP] = BcT;
    float (*MT)[LP] = CcT;
    float (*Xs)[LP] = BcT;             // staged after GEMM3 (ST dead)

    const int c = blockIdx.x, bh = blockIdx.y;
    const int b = bh >> 2, h = bh & 3;
    const int tid = threadIdx.x;
    const size_t row0 = (size_t)b * TSEQ;
    const int tb = c * CHUNK;
    const float Dh = Dparam[h];

    const int pS = tid >> 2;
    const int n16 = (tid & 3) * 16;
    const float* Sg = states + (size_t)(bh * NCHUNK + c) * 4096 + (size_t)pS * 64 + n16;
    const float4 sv0 = *(const float4*)(Sg + 0);
    const float4 sv1 = *(const float4*)(Sg + 4);
    const float4 sv2 = *(const float4*)(Sg + 8);
    const float4 sv3 = *(const float4*)(Sg + 12);

    if (tid < CHUNK) {
        const size_t o = (size_t)bh * TSEQ + tb + tid;
        const float la = laT[o];
        la_l[tid] = la;
        dt_l[tid] = dtT[o];
        a_l[tid] = __expf(la);
    }

    const int sg = tid & 15, st = tid >> 4;
    const int t4s = st * 4;

    {   // B -> BcT[n][i] (transposed store)
        const int ch = sg * 4;
        float w[4][4], bb[4];
#pragma unroll
        for (int j = 0; j < 4; ++j) {
            bb[j] = b_conv[DINNER + ch + j];
#pragma unroll
            for (int k = 0; k < 4; ++k) w[j][k] = W_conv[(DINNER + ch + j) * 4 + k];
        }
        float rx[4][7];
#pragma unroll
        for (int r = 0; r < 7; ++r) {
            const int tg = tb + t4s - 3 + r;
            float4 v = make_float4(0.f, 0.f, 0.f, 0.f);
            if (tg >= 0) v = *(const float4*)(bcbuf + (row0 + tg) * BCW2 + ch);
            rx[0][r] = v.x; rx[1][r] = v.y; rx[2][r] = v.z; rx[3][r] = v.w;
        }
#pragma unroll
        for (int j = 0; j < 4; ++j) {
            float o[4];
#pragma unroll
            for (int i = 0; i < 4; ++i)
                o[i] = siluf(fmaf(rx[j][i + 3], w[j][3], fmaf(rx[j][i + 2], w[j][2],
                             fmaf(rx[j][i + 1], w[j][1], fmaf(rx[j][i], w[j][0], bb[j])))));
            *(float4*)&BcT[ch + j][t4s] = make_float4(o[0], o[1], o[2], o[3]);
        }
    }
    {   // C -> CcT[n][t] (transposed store)
        const int ch = sg * 4;
        float w[4][4], bb[4];
#pragma unroll
        for (int j = 0; j < 4; ++j) {
            bb[j] = b_conv[DINNER + 64 + ch + j];
#pragma unroll
            for (int k = 0; k < 4; ++k) w[j][k] = W_conv[(DINNER + 64 + ch + j) * 4 + k];
        }
        float rx[4][7];
#pragma unroll
        for (int r = 0; r < 7; ++r) {
            const int tg = tb + t4s - 3 + r;
            float4 v = make_float4(0.f, 0.f, 0.f, 0.f);
            if (tg >= 0) v = *(const float4*)(bcbuf + (row0 + tg) * BCW2 + 64 + ch);
            rx[0][r] = v.x; rx[1][r] = v.y; rx[2][r] = v.z; rx[3][r] = v.w;
        }
#pragma unroll
        for (int j = 0; j < 4; ++j) {
            float o[4];
#pragma unroll
            for (int i = 0; i < 4; ++i)
                o[i] = siluf(fmaf(rx[j][i + 3], w[j][3], fmaf(rx[j][i + 2], w[j][2],
                             fmaf(rx[j][i + 1], w[j][1], fmaf(rx[j][i], w[j][0], bb[j])))));
            *(float4*)&CcT[ch + j][t4s] = make_float4(o[0], o[1], o[2], o[3]);
        }
    }
    __syncthreads();

    const int ti = tid & 15, tt = tid >> 4;
    const int i4 = ti * 4, t4 = tt * 4;

    // ---- GEMM1: M0[t][i] = C.B^T ----
    float m[4][4];
#pragma unroll
    for (int a = 0; a < 4; ++a)
#pragma unroll
        for (int d = 0; d < 4; ++d) m[a][d] = 0.f;
#pragma unroll 4
    for (int n = 0; n < 64; ++n) {
        const float4 cv = *(const float4*)&CcT[n][t4];
        const float4 bv = *(const float4*)&BcT[n][i4];
        const float ca[4] = {cv.x, cv.y, cv.z, cv.w};
        const float ba[4] = {bv.x, bv.y, bv.z, bv.w};
#pragma unroll
        for (int a = 0; a < 4; ++a)
#pragma unroll
            for (int d = 0; d < 4; ++d) m[a][d] = fmaf(ca[a], ba[d], m[a][d]);
    }
    // decay + causal mask (mask BEFORE exp)
    {
        float lat[4], lai[4], dti[4];
#pragma unroll
        for (int a = 0; a < 4; ++a) lat[a] = la_l[t4 + a];
#pragma unroll
        for (int d = 0; d < 4; ++d) { lai[d] = la_l[i4 + d]; dti[d] = dt_l[i4 + d]; }
#pragma unroll
        for (int a = 0; a < 4; ++a)
#pragma unroll
            for (int d = 0; d < 4; ++d) {
                if (i4 + d <= t4 + a)
                    m[a][d] = m[a][d] * dti[d] * __expf(lat[a] - lai[d]);
                else
                    m[a][d] = 0.f;
            }
    }
    __syncthreads();   // all waves done reading BcT

    // ---- ST[n][p] = S_old[p][n] (slot P) ----
    {
        const float sa[16] = {sv0.x, sv0.y, sv0.z, sv0.w, sv1.x, sv1.y, sv1.z, sv1.w,
                              sv2.x, sv2.y, sv2.z, sv2.w, sv3.x, sv3.y, sv3.z, sv3.w};
#pragma unroll
        for (int q = 0; q < 16; ++q) ST[n16 + q][pS] = sa[q];
    }
    __syncthreads();

    // ---- GEMM3: Y2[t][p] = C.S^T ----
    float y2[4][4];
#pragma unroll
    for (int a = 0; a < 4; ++a)
#pragma unroll
        for (int d = 0; d < 4; ++d) y2[a][d] = 0.f;
#pragma unroll 4
    for (int n = 0; n < 64; ++n) {
        const float4 cv = *(const float4*)&CcT[n][t4];
        const float4 sv = *(const float4*)&ST[n][i4];
        const float ca[4] = {cv.x, cv.y, cv.z, cv.w};
        const float sa[4] = {sv.x, sv.y, sv.z, sv.w};
#pragma unroll
        for (int a = 0; a < 4; ++a)
#pragma unroll
            for (int d = 0; d < 4; ++d) y2[a][d] = fmaf(ca[a], sa[d], y2[a][d]);
    }
    __syncthreads();   // GEMM3 done: ST (slot P) and Cc (slot Q) both dead

    // ---- MT[i][t] = M[t][i] (slot Q)  +  Xs[t][p] staging (slot P) ----
#pragma unroll
    for (int d = 0; d < 4; ++d)
        *(float4*)&MT[i4 + d][t4] = make_float4(m[0][d], m[1][d], m[2][d], m[3][d]);
    {   // X -> Xs[t][p]: conv+silu of x, this head's 64 channels
        const int ch = h * HEADDIM + sg * 4;
        float w[4][4], bb[4];
#pragma unroll
        for (int j = 0; j < 4; ++j) {
            bb[j] = b_conv[ch + j];
#pragma unroll
            for (int k = 0; k < 4; ++k) w[j][k] = W_conv[(ch + j) * 4 + k];
        }
        float rx[4][7];
#pragma unroll
        for (int r = 0; r < 7; ++r) {
            const int tg = tb + t4s - 3 + r;
            float4 v = make_float4(0.f, 0.f, 0.f, 0.f);
            if (tg >= 0) v = *(const float4*)(xbuf + (row0 + tg) * DINNER + ch);
            rx[0][r] = v.x; rx[1][r] = v.y; rx[2][r] = v.z; rx[3][r] = v.w;
        }
#pragma unroll
        for (int i = 0; i < 4; ++i) {
            float o[4];
#pragma unroll
            for (int j = 0; j < 4; ++j)
                o[j] = siluf(fmaf(rx[j][i + 3], w[j][3], fmaf(rx[j][i + 2], w[j][2],
                             fmaf(rx[j][i + 1], w[j][1], fmaf(rx[j][i], w[j][0], bb[j])))));
            *(float4*)&Xs[t4s + i][sg * 4] = make_float4(o[0], o[1], o[2], o[3]);
        }
    }
    __syncthreads();

    // ---- GEMM2: Yac[t][p] = M.X ----
    float yac[4][4];
#pragma unroll
    for (int a = 0; a < 4; ++a)
#pragma unroll
        for (int d = 0; d < 4; ++d) yac[a][d] = 0.f;
#pragma unroll 4
    for (int k = 0; k < CHUNK; ++k) {
        const float4 mv = *(const float4*)&MT[k][t4];
        const float4 xv = *(const float4*)&Xs[k][i4];
        const float ma[4] = {mv.x, mv.y, mv.z, mv.w};
        const float xa[4] = {xv.x, xv.y, xv.z, xv.w};
#pragma unroll
        for (int a = 0; a < 4; ++a)
#pragma unroll
            for (int d = 0; d < 4; ++d) yac[a][d] = fmaf(ma[a], xa[d], yac[a][d]);
    }

    // ---- epilogue: Y = Yac + a[t]*Y2 + D*X ; g = Y*silu(z) -> zbuf ----
#pragma unroll
    for (int a = 0; a < 4; ++a) {
        const int t = t4 + a;
        const float at = a_l[t];
        const float4 xv = *(const float4*)&Xs[t][i4];
        const float xa[4] = {xv.x, xv.y, xv.z, xv.w};
        float* zp = zbuf + (row0 + tb + t) * DINNER + h * HEADDIM + i4;
        const float4 zv = *(const float4*)zp;
        const float za[4] = {zv.x, zv.y, zv.z, zv.w};
        float g[4];
#pragma unroll
        for (int d = 0; d < 4; ++d) {
            const float Y = yac[a][d] + at * y2[a][d] + Dh * xa[d];
            g[d] = Y * siluf(za[d]);
        }
        *(float4*)zp = make_float4(g[0], g[1], g[2], g[3]);
    }
}

// ---------------------------------------------------------------------------
__launch_bounds__(256)
__global__ void rms_val(const float* __restrict__ g, const float* __restrict__ Wv,
                        const float* __restrict__ bval, float* __restrict__ values,
                        unsigned short* __restrict__ Ghi, unsigned short* __restrict__ Glo)
{
    const size_t tok = (size_t)blockIdx.x * 4 + (threadIdx.x >> 6);
    const int lane = threadIdx.x & 63;
    const float4 v = *(const float4*)(g + tok * DINNER + lane * 4);
    const float4 w = *(const float4*)(Wv + lane * 4);
    float ssq = v.x * v.x + v.y * v.y + v.z * v.z + v.w * v.w;
    float gw  = v.x * w.x + v.y * w.y + v.z * w.z + v.w * w.w;
#pragma unroll
    for (int d = 1; d < 64; d <<= 1) {
        ssq += __shfl_xor(ssq, d, 64);
        gw  += __shfl_xor(gw, d, 64);
    }
    const float rms = rsqrtf(ssq * (1.f / DINNER) + 1e-5f);
    u16x4 h, l;
    splitbf(v.x * rms, ((unsigned short*)&h)[0], ((unsigned short*)&l)[0]);
    splitbf(v.y * rms, ((unsigned short*)&h)[1], ((unsigned short*)&l)[1]);
    splitbf(v.z * rms, ((unsigned short*)&h)[2], ((unsigned short*)&l)[2]);
    splitbf(v.w * rms, ((unsigned short*)&h)[3], ((unsigned short*)&l)[3]);
    *(u16x4*)(Ghi + tok * DINNER + lane * 4) = h;
    *(u16x4*)(Glo + tok * DINNER + lane * 4) = l;
    if (lane == 0) values[tok] = gw * rms + bval[0];
}

// ---------------------------------------------------------------------------
extern "C" void kernel_launch(void* const* d_in, const int* in_sizes, int n_in,
                              void* d_out, int out_size, void* d_ws, size_t ws_size,
                              hipStream_t stream)
{
    (void)in_sizes; (void)n_in; (void)out_size; (void)ws_size;
    const float* obs     = (const float*)d_in[0];
    const float* W_enc   = (const float*)d_in[1];
    const float* b_enc   = (const float*)d_in[2];
    const float* W_in    = (const float*)d_in[3];
    const float* W_conv  = (const float*)d_in[4];
    const float* b_conv  = (const float*)d_in[5];
    const float* dt_bias = (const float*)d_in[6];
    const float* A_log   = (const float*)d_in[7];
    const float* Dp      = (const float*)d_in[8];
    const float* norm_w  = (const float*)d_in[9];
    const float* W_out   = (const float*)d_in[10];
    const float* W_act   = (const float*)d_in[11];
    const float* b_act   = (const float*)d_in[12];
    const float* W_val   = (const float*)d_in[13];
    const float* b_val   = (const float*)d_in[14];

    float* logits = (float*)d_out;
    float* values = logits + (size_t)NTOK * NACT;

    char* ws = (char*)d_ws;
    size_t off = 0;
    auto alloc = [&](size_t nbytes) {
        char* ptr = ws + off;
        off += (nbytes + 255) / 256 * 256;
        return ptr;
    };
    float* zbuf   = (float*)alloc((size_t)NTOK * DINNER * 4);   // z -> g in place
    float* xbuf   = (float*)alloc((size_t)NTOK * DINNER * 4);
    float* bcbuf  = (float*)alloc((size_t)NTOK * BCW2 * 4);
    float* dtcol  = (float*)alloc((size_t)NTOK * 4 * 4);
    // shared 134.2 MB region: obs-bf16 (3-4) -> states (5-8) -> g-bf16 (9-10)
    char*  shared = alloc((size_t)NTOK * OBSD * 2 * 2);
    unsigned short* Ahi = (unsigned short*)shared;
    unsigned short* Alo = Ahi + (size_t)NTOK * OBSD;
    float* states = (float*)shared;
    unsigned short* Ghi = (unsigned short*)shared;
    unsigned short* Glo = Ghi + (size_t)NTOK * DINNER;
    float* dtT    = (float*)alloc((size_t)NBATCH * NHEADS * TSEQ * 4);
    float* laT    = (float*)alloc((size_t)NBATCH * NHEADS * TSEQ * 4);
    float* dApb   = (float*)alloc(NBATCH * NHEADS * NCHUNK * 4);
    unsigned short* WcThi = (unsigned short*)alloc((size_t)NPPAD * OBSD * 2);
    unsigned short* WcTlo = (unsigned short*)alloc((size_t)NPPAD * OBSD * 2);
    float* bz     = (float*)alloc(NPPAD * 4);
    unsigned short* WhThi = (unsigned short*)alloc((size_t)NACT * DINNER * 2);
    unsigned short* WhTlo = (unsigned short*)alloc((size_t)NACT * DINNER * 2);
    float* Wv     = (float*)alloc(DINNER * 4);

    fuse_whead<<<DINNER, NACT, 0, stream>>>(W_out, W_act, W_val, norm_w, WhThi, WhTlo, Wv);
    make_wc<<<NPPAD, 256, 0, stream>>>(W_enc, W_in, b_enc, WcThi, WcTlo, bz);
    conv_obs<<<2048, 256, 0, stream>>>(obs, Ahi, Alo);
    mfma_gemm<1><<<dim3(NPPAD / 64, NTOK / 128), 256, 0, stream>>>(
        Ahi, Alo, WcThi, WcTlo, OBSD, bz, nullptr, zbuf, xbuf, bcbuf, dtcol);
    prep_scan<<<NBATCH * NHEADS * NCHUNK, 64, 0, stream>>>(
        dtcol, dt_bias, A_log, dtT, laT, dApb);
    scan_state<<<dim3(NCHUNK, NBATCH * NHEADS), 256, 0, stream>>>(
        xbuf, bcbuf, dtT, laT, W_conv, b_conv, states);
    chunk_scan<<<NBATCH * NHEADS * 16, 256, 0, stream>>>(states, dApb);
    scan_out<<<dim3(NCHUNK, NBATCH * NHEADS), 256, 0, stream>>>(
        xbuf, bcbuf, zbuf, dtT, laT, W_conv, b_conv, Dp, states);
    rms_val<<<NTOK / 4, 256, 0, stream>>>(zbuf, Wv, b_val, values, Ghi, Glo);
    mfma_gemm<0><<<dim3(1, NTOK / 128), 256, 0, stream>>>(
        Ghi, Glo, WhThi, WhTlo, DINNER, b_act, logits, nullptr, nullptr, nullptr, nullptr);
}

// Round 19
// 799.420 us; speedup vs baseline: 1.4708x; 1.0416x over previous
//
#include <hip/hip_runtime.h>
#include <math.h>

#define OBSD   256
#define TSEQ   4096
#define NBATCH 32
#define DMODEL 128
#define DSTATE 64
#define DINNER 256
#define NHEADS 4
#define HEADDIM 64
#define NPROJ  644
#define NPPAD  704   // in_proj N padded to 11*64
#define NTOK   (NBATCH*TSEQ)
#define CHUNK  64
#define NCHUNK (TSEQ/CHUNK)
#define NACT   64
#define BCW2   128   // bcbuf row width (B 64 | C 64)
#define LP     68    // padded LDS row stride (scan kernels)

typedef __attribute__((ext_vector_type(8))) short bf16x8;
typedef __attribute__((ext_vector_type(4))) float f32x4;
typedef __attribute__((ext_vector_type(8))) unsigned short u16x8;
typedef __attribute__((ext_vector_type(4))) unsigned short u16x4;

__device__ __forceinline__ float siluf(float x) { return x / (1.f + __expf(-x)); }

// round-to-nearest-even bf16 (bit pattern) and hi/lo split: v ~= hi + lo
__device__ __forceinline__ unsigned short bfhi(float v) {
    unsigned u = __float_as_uint(v);
    return (unsigned short)((u + 0x7FFFu + ((u >> 16) & 1u)) >> 16);
}
__device__ __forceinline__ void splitbf(float v, unsigned short& hi, unsigned short& lo) {
    hi = bfhi(v);
    const float hf = __uint_as_float((unsigned)hi << 16);
    lo = bfhi(v - hf);
}

// ---------------------------------------------------------------------------
// Split-bf16 MFMA GEMM (HW-verified round 10).
// r18 -> r19: SEG=1 stages A directly from fp32 (obs), splitting to bf16
// hi/lo in-register — deletes the separate conv_obs pass (same bytes/elem,
// identical split values => bit-identical output). SEG=0 keeps bf16 A path.
// ---------------------------------------------------------------------------
template<int SEG>
__launch_bounds__(256)
__global__ void mfma_gemm(const float* __restrict__ Af32,
                          const unsigned short* __restrict__ Ahi,
                          const unsigned short* __restrict__ Alo,
                          const unsigned short* __restrict__ BThi,
                          const unsigned short* __restrict__ BTlo,
                          int K, const float* __restrict__ bias,
                          float* __restrict__ C,
                          float* __restrict__ zbuf, float* __restrict__ xbuf,
                          float* __restrict__ bcbuf, float* __restrict__ dtcol)
{
    __shared__ __align__(16) unsigned short Ah[128][40], Al[128][40];
    __shared__ __align__(16) unsigned short Bh[64][40],  Bl[64][40];
    const int tid  = threadIdx.x;
    const int wave = tid >> 6, lane = tid & 63;
    const int l15 = lane & 15, l4 = lane >> 4;
    const int m0 = blockIdx.y * 128, n0 = blockIdx.x * 64;

    f32x4 acc[2][4];
#pragma unroll
    for (int rt = 0; rt < 2; ++rt)
#pragma unroll
        for (int ct = 0; ct < 4; ++ct) acc[rt][ct] = (f32x4){0.f, 0.f, 0.f, 0.f};

    const int ar  = tid >> 1;           // A row 0..127
    const int akc = (tid & 1) * 16;     // k chunk base
    const int br  = tid >> 2;           // B row (n)
    const int bkc = (tid & 3) * 8;

    for (int k0 = 0; k0 < K; k0 += 32) {
        if constexpr (SEG == 1) {
            // stage A from fp32, split in-register (replaces conv_obs)
            const float* ap = Af32 + (size_t)(m0 + ar) * K + k0 + akc;
#pragma unroll
            for (int half = 0; half < 2; ++half) {
                const float4 v0 = *(const float4*)(ap + half * 8);
                const float4 v1 = *(const float4*)(ap + half * 8 + 4);
                const float va[8] = {v0.x, v0.y, v0.z, v0.w, v1.x, v1.y, v1.z, v1.w};
                u16x8 hh, ll;
#pragma unroll
                for (int e = 0; e < 8; ++e)
                    splitbf(va[e], ((unsigned short*)&hh)[e], ((unsigned short*)&ll)[e]);
                *(u16x8*)&Ah[ar][akc + half * 8] = hh;
                *(u16x8*)&Al[ar][akc + half * 8] = ll;
            }
        } else {
            const size_t ab = (size_t)(m0 + ar) * K + k0 + akc;
            *(u16x8*)&Ah[ar][akc]     = *(const u16x8*)(Ahi + ab);
            *(u16x8*)&Ah[ar][akc + 8] = *(const u16x8*)(Ahi + ab + 8);
            *(u16x8*)&Al[ar][akc]     = *(const u16x8*)(Alo + ab);
            *(u16x8*)&Al[ar][akc + 8] = *(const u16x8*)(Alo + ab + 8);
        }
        {
            const size_t bb = (size_t)(n0 + br) * K + k0 + bkc;
            *(u16x8*)&Bh[br][bkc] = *(const u16x8*)(BThi + bb);
            *(u16x8*)&Bl[br][bkc] = *(const u16x8*)(BTlo + bb);
        }
        __syncthreads();

        const int kk = l4 * 8;
        bf16x8 ah[2], al[2], bh[4], bl[4];
#pragma unroll
        for (int rt = 0; rt < 2; ++rt) {
            const int r = wave * 32 + rt * 16 + l15;
            ah[rt] = *(const bf16x8*)&Ah[r][kk];
            al[rt] = *(const bf16x8*)&Al[r][kk];
        }
#pragma unroll
        for (int ct = 0; ct < 4; ++ct) {
            const int n = ct * 16 + l15;
            bh[ct] = *(const bf16x8*)&Bh[n][kk];
            bl[ct] = *(const bf16x8*)&Bl[n][kk];
        }
#pragma unroll
        for (int rt = 0; rt < 2; ++rt)
#pragma unroll
            for (int ct = 0; ct < 4; ++ct) {
                acc[rt][ct] = __builtin_amdgcn_mfma_f32_16x16x32_bf16(ah[rt], bh[ct], acc[rt][ct], 0, 0, 0);
                acc[rt][ct] = __builtin_amdgcn_mfma_f32_16x16x32_bf16(ah[rt], bl[ct], acc[rt][ct], 0, 0, 0);
                acc[rt][ct] = __builtin_amdgcn_mfma_f32_16x16x32_bf16(al[rt], bh[ct], acc[rt][ct], 0, 0, 0);
            }
        __syncthreads();
    }

#pragma unroll
    for (int rt = 0; rt < 2; ++rt) {
        const int rbase = m0 + wave * 32 + rt * 16 + l4 * 4;
#pragma unroll
        for (int ct = 0; ct < 4; ++ct) {
            const int cg = n0 + ct * 16 + l15;
            const float bv = bias[cg];
#pragma unroll
            for (int j = 0; j < 4; ++j) {
                const float v = acc[rt][ct][j] + bv;
                const size_t r = (size_t)(rbase + j);
                if constexpr (SEG == 0) {
                    C[r * NACT + cg] = v;
                } else {
                    if (cg < 256)      zbuf[r * DINNER + cg] = v;
                    else if (cg < 512) xbuf[r * DINNER + (cg - 256)] = v;
                    else if (cg < 640) bcbuf[r * BCW2 + (cg - 512)] = v;
                    else if (cg < NPROJ) dtcol[r * 4 + (cg - 640)] = v;
                }
            }
        }
    }
}

// ---------------------------------------------------------------------------
__global__ void make_wc(const float* __restrict__ W_enc, const float* __restrict__ W_in,
                        const float* __restrict__ b_enc,
                        unsigned short* __restrict__ WcThi, unsigned short* __restrict__ WcTlo,
                        float* __restrict__ bz)
{
    const int n = blockIdx.x;
    const int r = threadIdx.x;
    float v = 0.f;
    if (n < NPROJ)
        for (int k = 0; k < DMODEL; ++k)
            v = fmaf(W_enc[r * DMODEL + k], W_in[k * NPROJ + n], v);
    unsigned short hi, lo; splitbf(v, hi, lo);
    WcThi[n * OBSD + r] = hi;
    WcTlo[n * OBSD + r] = lo;
    if (r == 0) {
        float bv = 0.f;
        if (n < NPROJ)
            for (int k = 0; k < DMODEL; ++k)
                bv = fmaf(b_enc[k], W_in[k * NPROJ + n], bv);
        bz[n] = bv;
    }
}

// ---------------------------------------------------------------------------
__global__ void fuse_whead(const float* __restrict__ W_out, const float* __restrict__ W_act,
                           const float* __restrict__ W_val, const float* __restrict__ norm_w,
                           unsigned short* __restrict__ WhThi, unsigned short* __restrict__ WhTlo,
                           float* __restrict__ Wv)
{
    const int k = blockIdx.x;
    const int j = threadIdx.x;
    float s = 0.f;
    for (int m = 0; m < DMODEL; ++m)
        s = fmaf(W_out[k * DMODEL + m], W_act[m * NACT + j], s);
    s *= norm_w[k];
    unsigned short hi, lo; splitbf(s, hi, lo);
    WhThi[j * DINNER + k] = hi;
    WhTlo[j * DINNER + k] = lo;
    if (j == 0) {
        float sv = 0.f;
        for (int m = 0; m < DMODEL; ++m)
            sv = fmaf(W_out[k * DMODEL + m], W_val[m], sv);
        Wv[k] = sv * norm_w[k];
    }
}

// ---------------------------------------------------------------------------
__global__ void prep_scan(const float* __restrict__ dtcol, const float* __restrict__ dt_bias,
                          const float* __restrict__ A_log,
                          float* __restrict__ dtT, float* __restrict__ laT,
                          float* __restrict__ dApbuf)
{
    const int bc = blockIdx.x;
    const int bh = bc >> 6, c = bc & 63;
    const int b = bh >> 2, h = bh & 3;
    const int lane = threadIdx.x;
    const size_t tok = (size_t)b * TSEQ + c * CHUNK + lane;
    const float x = dtcol[tok * 4 + h] + dt_bias[h];
    const float dt = (x > 20.f) ? x : log1pf(expf(x));
    const float A = -expf(A_log[h]);
    float v = dt * A;
#pragma unroll
    for (int d = 1; d < 64; d <<= 1) {
        const float o = __shfl_up(v, d, 64);
        if (lane >= d) v += o;
    }
    const size_t o = (size_t)bh * TSEQ + c * CHUNK + lane;
    dtT[o] = dt;
    laT[o] = v;
    if (lane == 63) dApbuf[bh * NCHUNK + c] = __expf(v);
}

// ---------------------------------------------------------------------------
// Phase A: chunk-local states via GEMM (fp32 VALU — passed r9/r10/r17/r18).
// ---------------------------------------------------------------------------
__launch_bounds__(256)
__global__ void scan_state(const float* __restrict__ xbuf, const float* __restrict__ bcbuf,
                           const float* __restrict__ dtT, const float* __restrict__ laT,
                           const float* __restrict__ W_conv, const float* __restrict__ b_conv,
                           float* __restrict__ states)
{
    __shared__ float Xs[CHUNK][LP];
    __shared__ float Bw[CHUNK][LP];
    __shared__ float w_l[CHUNK];
    const int c = blockIdx.x, bh = blockIdx.y;
    const int b = bh >> 2, h = bh & 3;
    const int tid = threadIdx.x;
    const size_t row0 = (size_t)b * TSEQ;
    const int tb = c * CHUNK;

    if (tid < CHUNK) {
        const size_t o = (size_t)bh * TSEQ + tb;
        const float laLast = laT[o + CHUNK - 1];
        w_l[tid] = dtT[o + tid] * __expf(laLast - laT[o + tid]);
    }
    __syncthreads();

    const int sg = tid & 15, st = tid >> 4;
    const int t4 = st * 4;

    {
        const int ch = h * HEADDIM + sg * 4;
        float w[4][4], bb[4];
#pragma unroll
        for (int j = 0; j < 4; ++j) {
            bb[j] = b_conv[ch + j];
#pragma unroll
            for (int k = 0; k < 4; ++k) w[j][k] = W_conv[(ch + j) * 4 + k];
        }
        float rx[4][7];
#pragma unroll
        for (int r = 0; r < 7; ++r) {
            const int tg = tb + t4 - 3 + r;
            float4 v = make_float4(0.f, 0.f, 0.f, 0.f);
            if (tg >= 0) v = *(const float4*)(xbuf + (row0 + tg) * DINNER + ch);
            rx[0][r] = v.x; rx[1][r] = v.y; rx[2][r] = v.z; rx[3][r] = v.w;
        }
#pragma unroll
        for (int i = 0; i < 4; ++i) {
            float o[4];
#pragma unroll
            for (int j = 0; j < 4; ++j)
                o[j] = siluf(fmaf(rx[j][i + 3], w[j][3], fmaf(rx[j][i + 2], w[j][2],
                             fmaf(rx[j][i + 1], w[j][1], fmaf(rx[j][i], w[j][0], bb[j])))));
            *(float4*)&Xs[t4 + i][sg * 4] = make_float4(o[0], o[1], o[2], o[3]);
        }
    }
    {
        const int ch = sg * 4;
        float w[4][4], bb[4];
#pragma unroll
        for (int j = 0; j < 4; ++j) {
            bb[j] = b_conv[DINNER + ch + j];
#pragma unroll
            for (int k = 0; k < 4; ++k) w[j][k] = W_conv[(DINNER + ch + j) * 4 + k];
        }
        float rx[4][7];
#pragma unroll
        for (int r = 0; r < 7; ++r) {
            const int tg = tb + t4 - 3 + r;
            float4 v = make_float4(0.f, 0.f, 0.f, 0.f);
            if (tg >= 0) v = *(const float4*)(bcbuf + (row0 + tg) * BCW2 + ch);
            rx[0][r] = v.x; rx[1][r] = v.y; rx[2][r] = v.z; rx[3][r] = v.w;
        }
#pragma unroll
        for (int i = 0; i < 4; ++i) {
            const float wi = w_l[t4 + i];
            float o[4];
#pragma unroll
            for (int j = 0; j < 4; ++j)
                o[j] = wi * siluf(fmaf(rx[j][i + 3], w[j][3], fmaf(rx[j][i + 2], w[j][2],
                              fmaf(rx[j][i + 1], w[j][1], fmaf(rx[j][i], w[j][0], bb[j])))));
            *(float4*)&Bw[t4 + i][sg * 4] = make_float4(o[0], o[1], o[2], o[3]);
        }
    }
    __syncthreads();

    const int pn = tid & 15, pp = tid >> 4;
    const int n4 = pn * 4, p4 = pp * 4;
    float acc[4][4];
#pragma unroll
    for (int a = 0; a < 4; ++a)
#pragma unroll
        for (int d = 0; d < 4; ++d) acc[a][d] = 0.f;
#pragma unroll 4
    for (int i = 0; i < CHUNK; ++i) {
        const float4 xv = *(const float4*)&Xs[i][p4];
        const float4 bv = *(const float4*)&Bw[i][n4];
        const float xa[4] = {xv.x, xv.y, xv.z, xv.w};
        const float ba[4] = {bv.x, bv.y, bv.z, bv.w};
#pragma unroll
        for (int a = 0; a < 4; ++a)
#pragma unroll
            for (int d = 0; d < 4; ++d) acc[a][d] = fmaf(xa[a], ba[d], acc[a][d]);
    }
    const size_t so = (size_t)(bh * NCHUNK + c) * 4096;
#pragma unroll
    for (int a = 0; a < 4; ++a)
        *(float4*)(states + so + (size_t)(p4 + a) * 64 + n4) =
            make_float4(acc[a][0], acc[a][1], acc[a][2], acc[a][3]);
}

// ---------------------------------------------------------------------------
__global__ void chunk_scan(float* __restrict__ states, const float* __restrict__ dAprod)
{
    __shared__ float sdA[NCHUNK];
    const int bh = blockIdx.x >> 4;
    const int elem = ((blockIdx.x & 15) << 8) | threadIdx.x;
    if (threadIdx.x < NCHUNK) sdA[threadIdx.x] = dAprod[bh * NCHUNK + threadIdx.x];
    __syncthreads();
    const size_t base = (size_t)bh * NCHUNK * 4096 + elem;
    float s0 = 0.f;
    for (int c = 0; c < NCHUNK; ++c) {
        const size_t off = base + (size_t)c * 4096;
        const float Sc = states[off];
        states[off] = s0;
        s0 = fmaf(sdA[c], s0, Sc);
    }
}

// ---------------------------------------------------------------------------
// Phase B: outputs via 3 fp32 micro-GEMMs per (bh, chunk).
// 2-slot LDS (36 KB): Slot P = BcT -> ST -> Xs ; Slot Q = CcT -> MT (r18).
// ---------------------------------------------------------------------------
__launch_bounds__(256)
__global__ void scan_out(const float* __restrict__ xbuf, const float* __restrict__ bcbuf,
                         float* zbuf,
                         const float* __restrict__ dtT, const float* __restrict__ laT,
                         const float* __restrict__ W_conv, const float* __restrict__ b_conv,
                         const float* __restrict__ Dparam,
                         const float* __restrict__ states)
{
    __shared__ float BcT[CHUNK][LP];   // P: Bc[n][i] -> ST[n][p] -> Xs[t][p]
    __shared__ float CcT[CHUNK][LP];   // Q: Cc[n][t] -> MT[i][t]
    __shared__ float la_l[CHUNK], dt_l[CHUNK], a_l[CHUNK];
    float (*ST)[LP] = BcT;
    float (*MT)[LP] = CcT;
    float (*Xs)[LP] = BcT;             // staged after GEMM3 (ST dead)

    const int c = blockIdx.x, bh = blockIdx.y;
    const int b = bh >> 2, h = bh & 3;
    const int tid = threadIdx.x;
    const size_t row0 = (size_t)b * TSEQ;
    const int tb = c * CHUNK;
    const float Dh = Dparam[h];

    const int pS = tid >> 2;
    const int n16 = (tid & 3) * 16;
    const float* Sg = states + (size_t)(bh * NCHUNK + c) * 4096 + (size_t)pS * 64 + n16;
    const float4 sv0 = *(const float4*)(Sg + 0);
    const float4 sv1 = *(const float4*)(Sg + 4);
    const float4 sv2 = *(const float4*)(Sg + 8);
    const float4 sv3 = *(const float4*)(Sg + 12);

    if (tid < CHUNK) {
        const size_t o = (size_t)bh * TSEQ + tb + tid;
        const float la = laT[o];
        la_l[tid] = la;
        dt_l[tid] = dtT[o];
        a_l[tid] = __expf(la);
    }

    const int sg = tid & 15, st = tid >> 4;
    const int t4s = st * 4;

    {   // B -> BcT[n][i] (transposed store)
        const int ch = sg * 4;
        float w[4][4], bb[4];
#pragma unroll
        for (int j = 0; j < 4; ++j) {
            bb[j] = b_conv[DINNER + ch + j];
#pragma unroll
            for (int k = 0; k < 4; ++k) w[j][k] = W_conv[(DINNER + ch + j) * 4 + k];
        }
        float rx[4][7];
#pragma unroll
        for (int r = 0; r < 7; ++r) {
            const int tg = tb + t4s - 3 + r;
            float4 v = make_float4(0.f, 0.f, 0.f, 0.f);
            if (tg >= 0) v = *(const float4*)(bcbuf + (row0 + tg) * BCW2 + ch);
            rx[0][r] = v.x; rx[1][r] = v.y; rx[2][r] = v.z; rx[3][r] = v.w;
        }
#pragma unroll
        for (int j = 0; j < 4; ++j) {
            float o[4];
#pragma unroll
            for (int i = 0; i < 4; ++i)
                o[i] = siluf(fmaf(rx[j][i + 3], w[j][3], fmaf(rx[j][i + 2], w[j][2],
                             fmaf(rx[j][i + 1], w[j][1], fmaf(rx[j][i], w[j][0], bb[j])))));
            *(float4*)&BcT[ch + j][t4s] = make_float4(o[0], o[1], o[2], o[3]);
        }
    }
    {   // C -> CcT[n][t] (transposed store)
        const int ch = sg * 4;
        float w[4][4], bb[4];
#pragma unroll
        for (int j = 0; j < 4; ++j) {
            bb[j] = b_conv[DINNER + 64 + ch + j];
#pragma unroll
            for (int k = 0; k < 4; ++k) w[j][k] = W_conv[(DINNER + 64 + ch + j) * 4 + k];
        }
        float rx[4][7];
#pragma unroll
        for (int r = 0; r < 7; ++r) {
            const int tg = tb + t4s - 3 + r;
            float4 v = make_float4(0.f, 0.f, 0.f, 0.f);
            if (tg >= 0) v = *(const float4*)(bcbuf + (row0 + tg) * BCW2 + 64 + ch);
            rx[0][r] = v.x; rx[1][r] = v.y; rx[2][r] = v.z; rx[3][r] = v.w;
        }
#pragma unroll
        for (int j = 0; j < 4; ++j) {
            float o[4];
#pragma unroll
            for (int i = 0; i < 4; ++i)
                o[i] = siluf(fmaf(rx[j][i + 3], w[j][3], fmaf(rx[j][i + 2], w[j][2],
                             fmaf(rx[j][i + 1], w[j][1], fmaf(rx[j][i], w[j][0], bb[j])))));
            *(float4*)&CcT[ch + j][t4s] = make_float4(o[0], o[1], o[2], o[3]);
        }
    }
    __syncthreads();

    const int ti = tid & 15, tt = tid >> 4;
    const int i4 = ti * 4, t4 = tt * 4;

    // ---- GEMM1: M0[t][i] = C.B^T ----
    float m[4][4];
#pragma unroll
    for (int a = 0; a < 4; ++a)
#pragma unroll
        for (int d = 0; d < 4; ++d) m[a][d] = 0.f;
#pragma unroll 4
    for (int n = 0; n < 64; ++n) {
        const float4 cv = *(const float4*)&CcT[n][t4];
        const float4 bv = *(const float4*)&BcT[n][i4];
        const float ca[4] = {cv.x, cv.y, cv.z, cv.w};
        const float ba[4] = {bv.x, bv.y, bv.z, bv.w};
#pragma unroll
        for (int a = 0; a < 4; ++a)
#pragma unroll
            for (int d = 0; d < 4; ++d) m[a][d] = fmaf(ca[a], ba[d], m[a][d]);
    }
    // decay + causal mask (mask BEFORE exp)
    {
        float lat[4], lai[4], dti[4];
#pragma unroll
        for (int a = 0; a < 4; ++a) lat[a] = la_l[t4 + a];
#pragma unroll
        for (int d = 0; d < 4; ++d) { lai[d] = la_l[i4 + d]; dti[d] = dt_l[i4 + d]; }
#pragma unroll
        for (int a = 0; a < 4; ++a)
#pragma unroll
            for (int d = 0; d < 4; ++d) {
                if (i4 + d <= t4 + a)
                    m[a][d] = m[a][d] * dti[d] * __expf(lat[a] - lai[d]);
                else
                    m[a][d] = 0.f;
            }
    }
    __syncthreads();   // all waves done reading BcT

    // ---- ST[n][p] = S_old[p][n] (slot P) ----
    {
        const float sa[16] = {sv0.x, sv0.y, sv0.z, sv0.w, sv1.x, sv1.y, sv1.z, sv1.w,
                              sv2.x, sv2.y, sv2.z, sv2.w, sv3.x, sv3.y, sv3.z, sv3.w};
#pragma unroll
        for (int q = 0; q < 16; ++q) ST[n16 + q][pS] = sa[q];
    }
    __syncthreads();

    // ---- GEMM3: Y2[t][p] = C.S^T ----
    float y2[4][4];
#pragma unroll
    for (int a = 0; a < 4; ++a)
#pragma unroll
        for (int d = 0; d < 4; ++d) y2[a][d] = 0.f;
#pragma unroll 4
    for (int n = 0; n < 64; ++n) {
        const float4 cv = *(const float4*)&CcT[n][t4];
        const float4 sv = *(const float4*)&ST[n][i4];
        const float ca[4] = {cv.x, cv.y, cv.z, cv.w};
        const float sa[4] = {sv.x, sv.y, sv.z, sv.w};
#pragma unroll
        for (int a = 0; a < 4; ++a)
#pragma unroll
            for (int d = 0; d < 4; ++d) y2[a][d] = fmaf(ca[a], sa[d], y2[a][d]);
    }
    __syncthreads();   // GEMM3 done: ST (slot P) and Cc (slot Q) both dead

    // ---- MT[i][t] = M[t][i] (slot Q)  +  Xs[t][p] staging (slot P) ----
#pragma unroll
    for (int d = 0; d < 4; ++d)
        *(float4*)&MT[i4 + d][t4] = make_float4(m[0][d], m[1][d], m[2][d], m[3][d]);
    {   // X -> Xs[t][p]: conv+silu of x, this head's 64 channels
        const int ch = h * HEADDIM + sg * 4;
        float w[4][4], bb[4];
#pragma unroll
        for (int j = 0; j < 4; ++j) {
            bb[j] = b_conv[ch + j];
#pragma unroll
            for (int k = 0; k < 4; ++k) w[j][k] = W_conv[(ch + j) * 4 + k];
        }
        float rx[4][7];
#pragma unroll
        for (int r = 0; r < 7; ++r) {
            const int tg = tb + t4s - 3 + r;
            float4 v = make_float4(0.f, 0.f, 0.f, 0.f);
            if (tg >= 0) v = *(const float4*)(xbuf + (row0 + tg) * DINNER + ch);
            rx[0][r] = v.x; rx[1][r] = v.y; rx[2][r] = v.z; rx[3][r] = v.w;
        }
#pragma unroll
        for (int i = 0; i < 4; ++i) {
            float o[4];
#pragma unroll
            for (int j = 0; j < 4; ++j)
                o[j] = siluf(fmaf(rx[j][i + 3], w[j][3], fmaf(rx[j][i + 2], w[j][2],
                             fmaf(rx[j][i + 1], w[j][1], fmaf(rx[j][i], w[j][0], bb[j])))));
            *(float4*)&Xs[t4s + i][sg * 4] = make_float4(o[0], o[1], o[2], o[3]);
        }
    }
    __syncthreads();

    // ---- GEMM2: Yac[t][p] = M.X ----
    float yac[4][4];
#pragma unroll
    for (int a = 0; a < 4; ++a)
#pragma unroll
        for (int d = 0; d < 4; ++d) yac[a][d] = 0.f;
#pragma unroll 4
    for (int k = 0; k < CHUNK; ++k) {
        const float4 mv = *(const float4*)&MT[k][t4];
        const float4 xv = *(const float4*)&Xs[k][i4];
        const float ma[4] = {mv.x, mv.y, mv.z, mv.w};
        const float xa[4] = {xv.x, xv.y, xv.z, xv.w};
#pragma unroll
        for (int a = 0; a < 4; ++a)
#pragma unroll
            for (int d = 0; d < 4; ++d) yac[a][d] = fmaf(ma[a], xa[d], yac[a][d]);
    }

    // ---- epilogue: Y = Yac + a[t]*Y2 + D*X ; g = Y*silu(z) -> zbuf ----
#pragma unroll
    for (int a = 0; a < 4; ++a) {
        const int t = t4 + a;
        const float at = a_l[t];
        const float4 xv = *(const float4*)&Xs[t][i4];
        const float xa[4] = {xv.x, xv.y, xv.z, xv.w};
        float* zp = zbuf + (row0 + tb + t) * DINNER + h * HEADDIM + i4;
        const float4 zv = *(const float4*)zp;
        const float za[4] = {zv.x, zv.y, zv.z, zv.w};
        float g[4];
#pragma unroll
        for (int d = 0; d < 4; ++d) {
            const float Y = yac[a][d] + at * y2[a][d] + Dh * xa[d];
            g[d] = Y * siluf(za[d]);
        }
        *(float4*)zp = make_float4(g[0], g[1], g[2], g[3]);
    }
}

// ---------------------------------------------------------------------------
__launch_bounds__(256)
__global__ void rms_val(const float* __restrict__ g, const float* __restrict__ Wv,
                        const float* __restrict__ bval, float* __restrict__ values,
                        unsigned short* __restrict__ Ghi, unsigned short* __restrict__ Glo)
{
    const size_t tok = (size_t)blockIdx.x * 4 + (threadIdx.x >> 6);
    const int lane = threadIdx.x & 63;
    const float4 v = *(const float4*)(g + tok * DINNER + lane * 4);
    const float4 w = *(const float4*)(Wv + lane * 4);
    float ssq = v.x * v.x + v.y * v.y + v.z * v.z + v.w * v.w;
    float gw  = v.x * w.x + v.y * w.y + v.z * w.z + v.w * w.w;
#pragma unroll
    for (int d = 1; d < 64; d <<= 1) {
        ssq += __shfl_xor(ssq, d, 64);
        gw  += __shfl_xor(gw, d, 64);
    }
    const float rms = rsqrtf(ssq * (1.f / DINNER) + 1e-5f);
    u16x4 h, l;
    splitbf(v.x * rms, ((unsigned short*)&h)[0], ((unsigned short*)&l)[0]);
    splitbf(v.y * rms, ((unsigned short*)&h)[1], ((unsigned short*)&l)[1]);
    splitbf(v.z * rms, ((unsigned short*)&h)[2], ((unsigned short*)&l)[2]);
    splitbf(v.w * rms, ((unsigned short*)&h)[3], ((unsigned short*)&l)[3]);
    *(u16x4*)(Ghi + tok * DINNER + lane * 4) = h;
    *(u16x4*)(Glo + tok * DINNER + lane * 4) = l;
    if (lane == 0) values[tok] = gw * rms + bval[0];
}

// ---------------------------------------------------------------------------
extern "C" void kernel_launch(void* const* d_in, const int* in_sizes, int n_in,
                              void* d_out, int out_size, void* d_ws, size_t ws_size,
                              hipStream_t stream)
{
    (void)in_sizes; (void)n_in; (void)out_size; (void)ws_size;
    const float* obs     = (const float*)d_in[0];
    const float* W_enc   = (const float*)d_in[1];
    const float* b_enc   = (const float*)d_in[2];
    const float* W_in    = (const float*)d_in[3];
    const float* W_conv  = (const float*)d_in[4];
    const float* b_conv  = (const float*)d_in[5];
    const float* dt_bias = (const float*)d_in[6];
    const float* A_log   = (const float*)d_in[7];
    const float* Dp      = (const float*)d_in[8];
    const float* norm_w  = (const float*)d_in[9];
    const float* W_out   = (const float*)d_in[10];
    const float* W_act   = (const float*)d_in[11];
    const float* b_act   = (const float*)d_in[12];
    const float* W_val   = (const float*)d_in[13];
    const float* b_val   = (const float*)d_in[14];

    float* logits = (float*)d_out;
    float* values = logits + (size_t)NTOK * NACT;

    char* ws = (char*)d_ws;
    size_t off = 0;
    auto alloc = [&](size_t nbytes) {
        char* ptr = ws + off;
        off += (nbytes + 255) / 256 * 256;
        return ptr;
    };
    float* zbuf   = (float*)alloc((size_t)NTOK * DINNER * 4);   // z -> g in place
    float* xbuf   = (float*)alloc((size_t)NTOK * DINNER * 4);
    float* bcbuf  = (float*)alloc((size_t)NTOK * BCW2 * 4);
    float* dtcol  = (float*)alloc((size_t)NTOK * 4 * 4);
    // shared 134.2 MB region: states (scan) -> g-bf16 (rms_val/logits)
    char*  shared = alloc((size_t)NTOK * OBSD * 2 * 2);
    float* states = (float*)shared;
    unsigned short* Ghi = (unsigned short*)shared;
    unsigned short* Glo = Ghi + (size_t)NTOK * DINNER;
    float* dtT    = (float*)alloc((size_t)NBATCH * NHEADS * TSEQ * 4);
    float* laT    = (float*)alloc((size_t)NBATCH * NHEADS * TSEQ * 4);
    float* dApb   = (float*)alloc(NBATCH * NHEADS * NCHUNK * 4);
    unsigned short* WcThi = (unsigned short*)alloc((size_t)NPPAD * OBSD * 2);
    unsigned short* WcTlo = (unsigned short*)alloc((size_t)NPPAD * OBSD * 2);
    float* bz     = (float*)alloc(NPPAD * 4);
    unsigned short* WhThi = (unsigned short*)alloc((size_t)NACT * DINNER * 2);
    unsigned short* WhTlo = (unsigned short*)alloc((size_t)NACT * DINNER * 2);
    float* Wv     = (float*)alloc(DINNER * 4);

    fuse_whead<<<DINNER, NACT, 0, stream>>>(W_out, W_act, W_val, norm_w, WhThi, WhTlo, Wv);
    make_wc<<<NPPAD, 256, 0, stream>>>(W_enc, W_in, b_enc, WcThi, WcTlo, bz);
    // in_proj: A staged from fp32 obs, split in-register (conv_obs deleted)
    mfma_gemm<1><<<dim3(NPPAD / 64, NTOK / 128), 256, 0, stream>>>(
        obs, nullptr, nullptr, WcThi, WcTlo, OBSD, bz, nullptr, zbuf, xbuf, bcbuf, dtcol);
    prep_scan<<<NBATCH * NHEADS * NCHUNK, 64, 0, stream>>>(
        dtcol, dt_bias, A_log, dtT, laT, dApb);
    scan_state<<<dim3(NCHUNK, NBATCH * NHEADS), 256, 0, stream>>>(
        xbuf, bcbuf, dtT, laT, W_conv, b_conv, states);
    chunk_scan<<<NBATCH * NHEADS * 16, 256, 0, stream>>>(states, dApb);
    scan_out<<<dim3(NCHUNK, NBATCH * NHEADS), 256, 0, stream>>>(
        xbuf, bcbuf, zbuf, dtT, laT, W_conv, b_conv, Dp, states);
    rms_val<<<NTOK / 4, 256, 0, stream>>>(zbuf, Wv, b_val, values, Ghi, Glo);
    mfma_gemm<0><<<dim3(1, NTOK / 128), 256, 0, stream>>>(
        nullptr, Ghi, Glo, WhThi, WhTlo, DINNER, b_act, logits, nullptr, nullptr, nullptr, nullptr);
}